// Round 12
// baseline (245.918 us; speedup 1.0000x reference)
//
#include <hip/hip_runtime.h>

#define IN_DIM  128
#define HIDDEN  512
#define NCLASS  10
#define TSTEPS  512
#define BATCH   512
#define BETA    0.9f
#define THRESH  0.15f

typedef __attribute__((ext_vector_type(8))) short bf16x8;
typedef __attribute__((ext_vector_type(4))) float f32x4;

__device__ __forceinline__ unsigned short f2bf_rne(float f) {
    unsigned int u = __float_as_uint(f);
    u += 0x7FFFu + ((u >> 16) & 1u);
    return (unsigned short)(u >> 16);
}
__device__ __forceinline__ float bf2f(unsigned short h) {
    return __uint_as_float(((unsigned int)h) << 16);
}

// 8 f32 (scaled by s) -> hi bf16x8 + residual-lo bf16x8 (fp32-accurate split)
__device__ __forceinline__ void cvt8s(const float4 a, const float4 b, float s,
                                      bf16x8* hi, bf16x8* lo) {
    float v[8] = {a.x * s, a.y * s, a.z * s, a.w * s,
                  b.x * s, b.y * s, b.z * s, b.w * s};
#pragma unroll
    for (int e = 0; e < 8; ++e) {
        unsigned short h = f2bf_rne(v[e]);
        (*hi)[e] = (short)h;
        (*lo)[e] = (short)f2bf_rne(v[e] - bf2f(h));
    }
}

// ---------- Pass 1: repack x into LANE-LINEAR MFMA fragment tiles ----------
// tile(bblk,t) = 8KB: hi[2048 shorts] then lo[2048 shorts].
// Fragment element for wave-lane i, k-chunk kf at short index kf*512 + i*8
// => each wave ds_read_b128 covers 1KB contiguous -> conflict-free.
__global__ __launch_bounds__(256, 4) void conv_x2(
    const float* __restrict__ x, unsigned short* __restrict__ xt)
{
    const int bid  = blockIdx.x;          // bblk*512 + t
    const int bblk = bid >> 9;
    const int t    = bid & 511;
    const int g    = threadIdx.x;         // 0..255
    const int kf   = g >> 6;
    const int i    = g & 63;
    const int l15  = i & 15;
    const int lg   = i >> 4;

    const float* src = x + ((size_t)(bblk * 16 + l15) * TSTEPS + t) * IN_DIM
                         + kf * 32 + lg * 8;
    const float4* p = reinterpret_cast<const float4*>(src);
    bf16x8 h, l;
    cvt8s(p[0], p[1], 2.0f, &h, &l);

    unsigned short* tile = xt + ((size_t)bblk * TSTEPS + t) * 4096;
    *(bf16x8*)(tile + g * 8)        = h;   // g*8 == kf*512 + i*8
    *(bf16x8*)(tile + 2048 + g * 8) = l;
}

// ---------- Pass 2: fused SNN, 2-wave blocks + inline-asm LDS pipeline ----
// Wave = 16b x 32h (2 n-subtiles; W 64 VGPR pinned). Block = 2 waves =
// 16b x 64h -> grid 256. LDS reads halve vs 4-wave (16 b128/t/CU).
// Per iter t: [vmcnt(20) -> barrier] -> stage tile t+7 (4 gload_lds) ->
// 8 asm ds_read slot(t+1) -> NEXT regs -> lgkmcnt(8)+sched_barrier(0)
// (CURRENT frags, read LAST iter, now guaranteed landed; this iter's 8 stay
// in flight) -> 24 MFMA + recurrence. asm volatile order is binding: the
// compiler cannot sink the reads to their consumers (R8-R10's failure).
__global__ __launch_bounds__(128, 1) void snn_mfma_a(
    const unsigned short* __restrict__ xt,
    const float* __restrict__ W1, const float* __restrict__ b1,
    float* __restrict__ cnt_ws)
{
    __shared__ char ring[8][8192];   // 64 KB

    const int bid  = blockIdx.x;
    const int hblk = bid >> 5;     // 0..7 ; bid%8==bblk%8 -> x-sharers co-XCD
    const int bblk = bid & 31;
    const int b0   = bblk * 16;
    const int tid  = threadIdx.x;  // 0..127
    const int wave = tid >> 6;     // 0..1
    const int lane = tid & 63;
    const int l15  = lane & 15;
    const int lg   = lane >> 4;
    const int hbase = hblk * 64 + wave * 32;   // this wave: h [hbase, hbase+32)

    // ---- W fragments for 2 n-subtiles (fp32->hi/lo once, pinned) ----
    bf16x8 whi0[4], wlo0[4], whi1[4], wlo1[4];
    {
        const float* wp0 = W1 + (size_t)(hbase + l15) * IN_DIM + lg * 8;
        const float* wp1 = W1 + (size_t)(hbase + 16 + l15) * IN_DIM + lg * 8;
#pragma unroll
        for (int kf = 0; kf < 4; ++kf) {
            const float4* p0 = reinterpret_cast<const float4*>(wp0 + kf * 32);
            const float4* p1 = reinterpret_cast<const float4*>(wp1 + kf * 32);
            cvt8s(p0[0], p0[1], 1.0f, &whi0[kf], &wlo0[kf]);
            cvt8s(p1[0], p1[1], 1.0f, &whi1[kf], &wlo1[kf]);
        }
    }
    const float b1h0 = b1[hbase + l15];
    const float b1h1 = b1[hbase + 16 + l15];

    const char* gb = (const char*)xt + (size_t)bblk * TSTEPS * 8192;
    char* lsb = &ring[0][0];
    const int woff   = wave * 4096;       // this wave stages 4KB of each tile
    const int lane16 = lane * 16;
    // 32-bit LDS byte address for asm ds_read (per-lane)
    const unsigned lbase =
        (unsigned)(unsigned long long)(__attribute__((address_space(3))) char*)&ring[0][0]
        + (unsigned)lane16;

    f32x4 mem0 = {0.f, 0.f, 0.f, 0.f}, cnt0 = {0.f, 0.f, 0.f, 0.f};
    f32x4 mem1 = {0.f, 0.f, 0.f, 0.f}, cnt1 = {0.f, 0.f, 0.f, 0.f};

#define STAGE(TT, SLOT)                                                        \
    {                                                                          \
        const char* g_ = gb + (size_t)(TT) * 8192 + woff + lane16;             \
        char* l_ = lsb + (SLOT) * 8192 + woff;                                 \
        __builtin_amdgcn_global_load_lds((const __attribute__((address_space(1))) void*)g_,          (__attribute__((address_space(3))) void*)l_,          16, 0, 0); \
        __builtin_amdgcn_global_load_lds((const __attribute__((address_space(1))) void*)(g_ + 1024), (__attribute__((address_space(3))) void*)(l_ + 1024), 16, 0, 0); \
        __builtin_amdgcn_global_load_lds((const __attribute__((address_space(1))) void*)(g_ + 2048), (__attribute__((address_space(3))) void*)(l_ + 2048), 16, 0, 0); \
        __builtin_amdgcn_global_load_lds((const __attribute__((address_space(1))) void*)(g_ + 3072), (__attribute__((address_space(3))) void*)(l_ + 3072), 16, 0, 0); \
    }

#define RD1(OFF, DST)                                                          \
    asm volatile("ds_read_b128 %0, %1 offset:%c2"                              \
                 : "=&v"(DST) : "v"(lbase), "i"(OFF))

#define RD8A(S, FH, FL)                                                        \
    RD1((S) * 8192 + 0,    FH[0]);                                             \
    RD1((S) * 8192 + 1024, FH[1]);                                             \
    RD1((S) * 8192 + 2048, FH[2]);                                             \
    RD1((S) * 8192 + 3072, FH[3]);                                             \
    RD1((S) * 8192 + 4096, FL[0]);                                             \
    RD1((S) * 8192 + 5120, FL[1]);                                             \
    RD1((S) * 8192 + 6144, FL[2]);                                             \
    RD1((S) * 8192 + 7168, FL[3]);

#define MFMA2(FH, FL)                                                          \
    {                                                                          \
        f32x4 chh0 = {b1h0, b1h0, b1h0, b1h0};                                 \
        f32x4 chl0 = {0.f, 0.f, 0.f, 0.f}, clh0 = {0.f, 0.f, 0.f, 0.f};        \
        f32x4 chh1 = {b1h1, b1h1, b1h1, b1h1};                                 \
        f32x4 chl1 = {0.f, 0.f, 0.f, 0.f}, clh1 = {0.f, 0.f, 0.f, 0.f};        \
        _Pragma("unroll")                                                      \
        for (int kf = 0; kf < 4; ++kf) {                                       \
            chh0 = __builtin_amdgcn_mfma_f32_16x16x32_bf16(FH[kf], whi0[kf], chh0, 0, 0, 0); \
            chl0 = __builtin_amdgcn_mfma_f32_16x16x32_bf16(FH[kf], wlo0[kf], chl0, 0, 0, 0); \
            clh0 = __builtin_amdgcn_mfma_f32_16x16x32_bf16(FL[kf], whi0[kf], clh0, 0, 0, 0); \
            chh1 = __builtin_amdgcn_mfma_f32_16x16x32_bf16(FH[kf], whi1[kf], chh1, 0, 0, 0); \
            chl1 = __builtin_amdgcn_mfma_f32_16x16x32_bf16(FH[kf], wlo1[kf], chl1, 0, 0, 0); \
            clh1 = __builtin_amdgcn_mfma_f32_16x16x32_bf16(FL[kf], whi1[kf], clh1, 0, 0, 0); \
        }                                                                      \
        _Pragma("unroll")                                                      \
        for (int r = 0; r < 4; ++r) {                                          \
            float cur0 = (chh0[r] + chl0[r]) + clh0[r];                        \
            float dec0 = fmaf(BETA, mem0[r], cur0);                            \
            mem0[r] = (mem0[r] > THRESH) ? (dec0 - THRESH) : dec0;             \
            cnt0[r] += (mem0[r] > THRESH) ? 1.0f : 0.0f;                       \
            float cur1 = (chh1[r] + chl1[r]) + clh1[r];                        \
            float dec1 = fmaf(BETA, mem1[r], cur1);                            \
            mem1[r] = (mem1[r] > THRESH) ? (dec1 - THRESH) : dec1;             \
            cnt1[r] += (mem1[r] > THRESH) ? 1.0f : 0.0f;                       \
        }                                                                      \
    }

// J = compile-time 0..7 (slots literal); tb = runtime t-base of this window.
#define ITER(J, CH, CL, NH, NL)                                                \
    {                                                                          \
        asm volatile("s_waitcnt vmcnt(20)" ::: "memory");                      \
        __builtin_amdgcn_s_barrier();                                          \
        asm volatile("" ::: "memory");                                         \
        { int tt = tb + (J) + 7; if (tt > TSTEPS - 1) tt = TSTEPS - 1;         \
          STAGE(tt, ((J) + 7) & 7) }                                           \
        RD8A(((J) + 1) & 7, NH, NL)                                            \
        asm volatile("s_waitcnt lgkmcnt(8)" ::: "memory");                     \
        __builtin_amdgcn_sched_barrier(0);                                     \
        MFMA2(CH, CL)                                                          \
    }

    // double-buffered A fragments (asm outputs -> live ranges pinned)
    bf16x8 fAh[4], fAl[4], fBh[4], fBl[4];

    // prologue: drain W/b1 loads; stage tiles 0..6 (28 loads); tile0 -> fA
    asm volatile("s_waitcnt vmcnt(0)" ::: "memory");
#pragma unroll
    for (int j = 0; j < 7; ++j)
        STAGE(j, j)
    asm volatile("s_waitcnt vmcnt(24)" ::: "memory");   // my tile-0 loads done
    __builtin_amdgcn_s_barrier();                        // everyone's done
    asm volatile("" ::: "memory");
    RD8A(0, fAh, fAl)   // 8 outstanding; drained by ITER(0)'s lgkmcnt(8)

    for (int w = 0; w < TSTEPS / 8; ++w) {
        const int tb = w * 8;
        ITER(0, fAh, fAl, fBh, fBl)
        ITER(1, fBh, fBl, fAh, fAl)
        ITER(2, fAh, fAl, fBh, fBl)
        ITER(3, fBh, fBl, fAh, fAl)
        ITER(4, fAh, fAl, fBh, fBl)
        ITER(5, fBh, fBl, fAh, fAl)
        ITER(6, fAh, fAl, fBh, fBl)
        ITER(7, fBh, fBl, fAh, fAl)
    }
#undef ITER
#undef MFMA2
#undef RD8A
#undef RD1
#undef STAGE

    // store spike counts; C-layout row = lg*4+r, col = l15 (per n-subtile)
    float* cp0 = cnt_ws + (size_t)b0 * HIDDEN + hbase + l15;
    float* cp1 = cnt_ws + (size_t)b0 * HIDDEN + hbase + 16 + l15;
#pragma unroll
    for (int r = 0; r < 4; ++r) {
        cp0[(size_t)(lg * 4 + r) * HIDDEN] = cnt0[r];
        cp1[(size_t)(lg * 4 + r) * HIDDEN] = cnt1[r];
    }
}

// ---------- Fallback (proven R2 path) if ws too small ----------
__global__ __launch_bounds__(256, 1) void snn_mfma_lds(
    const float* __restrict__ x, const float* __restrict__ W1,
    const float* __restrict__ b1, float* __restrict__ cnt_ws)
{
    __shared__ short ldsA[2][2][16 * IN_DIM];
    const int bid  = blockIdx.x;
    const int hblk = bid >> 5;
    const int bblk = bid & 31;
    const int b0   = bblk * 16;
    const int tid  = threadIdx.x;
    const int wave = tid >> 6;
    const int lane = tid & 63;
    const int l15  = lane & 15;
    const int lg   = lane >> 4;
    const int hbase = hblk * 64 + wave * 16;

    bf16x8 whi[4], wlo[4];
    {
        const float* wp = W1 + (size_t)(hbase + l15) * IN_DIM + lg * 8;
#pragma unroll
        for (int kf = 0; kf < 4; ++kf) {
            const float4* p = reinterpret_cast<const float4*>(wp + kf * 32);
            cvt8s(p[0], p[1], 1.0f, &whi[kf], &wlo[kf]);
        }
    }
    const float b1h = b1[hbase + l15];
    const int m_w  = wave * 4 + lg;
    const int widx = m_w * IN_DIM + ((l15 ^ (m_w & 7)) * 8);
    const float* xrow = x + ((size_t)(b0 + m_w) * TSTEPS) * IN_DIM + l15 * 8;
    int ridx[4];
#pragma unroll
    for (int kf = 0; kf < 4; ++kf)
        ridx[kf] = l15 * IN_DIM + (((lg + 4 * kf) ^ (l15 & 7)) * 8);

    f32x4 mem = {0.f, 0.f, 0.f, 0.f};
    f32x4 cnt = {0.f, 0.f, 0.f, 0.f};
    {
        const float4* p = reinterpret_cast<const float4*>(xrow);
        bf16x8 h8, l8;
        cvt8s(p[0], p[1], 2.0f, &h8, &l8);
        *(bf16x8*)&ldsA[0][0][widx] = h8;
        *(bf16x8*)&ldsA[0][1][widx] = l8;
    }
    float4 rA0, rA1, rB0, rB1;
    {
        const float4* p1 = reinterpret_cast<const float4*>(xrow + 1 * IN_DIM);
        rA0 = p1[0]; rA1 = p1[1];
        const float4* p2 = reinterpret_cast<const float4*>(xrow + 2 * IN_DIM);
        rB0 = p2[0]; rB1 = p2[1];
    }
    __syncthreads();

#define SNN_BODY(T_CUR, RC0, RC1)                                              \
    {                                                                          \
        const int buf = (T_CUR) & 1;                                           \
        if ((T_CUR) + 1 < TSTEPS) {                                            \
            bf16x8 h8, l8;                                                     \
            cvt8s(RC0, RC1, 2.0f, &h8, &l8);                                   \
            *(bf16x8*)&ldsA[buf ^ 1][0][widx] = h8;                            \
            *(bf16x8*)&ldsA[buf ^ 1][1][widx] = l8;                            \
        }                                                                      \
        bf16x8 ahi[4], alo[4];                                                 \
        _Pragma("unroll")                                                      \
        for (int kf = 0; kf < 4; ++kf) {                                       \
            ahi[kf] = *(const bf16x8*)&ldsA[buf][0][ridx[kf]];                 \
            alo[kf] = *(const bf16x8*)&ldsA[buf][1][ridx[kf]];                 \
        }                                                                      \
        {                                                                      \
            int tld = (T_CUR) + 3;                                             \
            if (tld > TSTEPS - 1) tld = TSTEPS - 1;                            \
            const float4* p = reinterpret_cast<const float4*>(                 \
                xrow + (size_t)tld * IN_DIM);                                  \
            RC0 = p[0]; RC1 = p[1];                                            \
        }                                                                      \
        f32x4 chh = {b1h, b1h, b1h, b1h};                                      \
        f32x4 chl = {0.f, 0.f, 0.f, 0.f};                                      \
        f32x4 clh = {0.f, 0.f, 0.f, 0.f};                                      \
        _Pragma("unroll")                                                      \
        for (int kf = 0; kf < 4; ++kf) {                                       \
            chh = __builtin_amdgcn_mfma_f32_16x16x32_bf16(ahi[kf], whi[kf], chh, 0, 0, 0); \
            chl = __builtin_amdgcn_mfma_f32_16x16x32_bf16(ahi[kf], wlo[kf], chl, 0, 0, 0); \
            clh = __builtin_amdgcn_mfma_f32_16x16x32_bf16(alo[kf], whi[kf], clh, 0, 0, 0); \
        }                                                                      \
        _Pragma("unroll")                                                      \
        for (int r = 0; r < 4; ++r) {                                          \
            float cur = (chh[r] + chl[r]) + clh[r];                            \
            float dec = fmaf(BETA, mem[r], cur);                               \
            mem[r] = (mem[r] > THRESH) ? (dec - THRESH) : dec;                 \
            cnt[r] += (mem[r] > THRESH) ? 1.0f : 0.0f;                         \
        }                                                                      \
        __syncthreads();                                                       \
    }

    for (int t = 0; t < TSTEPS; t += 2) {
        SNN_BODY(t,     rA0, rA1)
        SNN_BODY(t + 1, rB0, rB1)
    }
#undef SNN_BODY

    float* cp = cnt_ws + (size_t)b0 * HIDDEN + hbase + l15;
#pragma unroll
    for (int r = 0; r < 4; ++r)
        cp[(size_t)(lg * 4 + r) * HIDDEN] = cnt[r];
}

// out[b,c] = (sum_h cnt[b,h] * W2[c,h]) / T + b2[c]
__global__ __launch_bounds__(64, 1) void snn_out(
    const float* __restrict__ cnt_ws, const float* __restrict__ W2,
    const float* __restrict__ b2, float* __restrict__ out)
{
    const int b = blockIdx.x;
    const int lane = threadIdx.x;
    float c8[8];
#pragma unroll
    for (int j = 0; j < 8; ++j)
        c8[j] = cnt_ws[(size_t)b * HIDDEN + lane + 64 * j];
#pragma unroll
    for (int c = 0; c < NCLASS; ++c) {
        float s = 0.f;
#pragma unroll
        for (int j = 0; j < 8; ++j)
            s = fmaf(c8[j], W2[c * HIDDEN + lane + 64 * j], s);
#pragma unroll
        for (int off = 32; off >= 1; off >>= 1)
            s += __shfl_xor(s, off, 64);
        if (lane == c)
            out[(size_t)b * NCLASS + c] = s * (1.0f / (float)TSTEPS) + b2[c];
    }
}

extern "C" void kernel_launch(void* const* d_in, const int* in_sizes, int n_in,
                              void* d_out, int out_size, void* d_ws, size_t ws_size,
                              hipStream_t stream) {
    const float* x  = (const float*)d_in[0];
    const float* W1 = (const float*)d_in[1];
    const float* b1 = (const float*)d_in[2];
    const float* W2 = (const float*)d_in[3];
    const float* b2 = (const float*)d_in[4];
    float* out = (float*)d_out;

    const size_t NX = (size_t)BATCH * TSTEPS * IN_DIM;      // 33.55M elems
    float* cnt_ws = (float*)d_ws;                           // [B, H], 1 MB
    unsigned short* xt = (unsigned short*)((char*)d_ws + (1u << 20));
    const size_t need = (1u << 20) + 2 * NX * sizeof(unsigned short);

    if (ws_size >= need) {
        conv_x2<<<dim3(32 * TSTEPS), dim3(256), 0, stream>>>(x, xt);
        snn_mfma_a<<<dim3(256), dim3(128), 0, stream>>>(xt, W1, b1, cnt_ws);
    } else {
        snn_mfma_lds<<<dim3(256), dim3(256), 0, stream>>>(x, W1, b1, cnt_ws);
    }
    snn_out<<<dim3(BATCH), dim3(64), 0, stream>>>(cnt_ws, W2, b2, out);
}

// Round 13
// 173.679 us; speedup vs baseline: 1.4159x; 1.4159x over previous
//
#include <hip/hip_runtime.h>

#define IN_DIM  128
#define HIDDEN  512
#define NCLASS  10
#define TSTEPS  512
#define BATCH   512
#define BETA    0.9f
#define THRESH  0.15f

typedef __attribute__((ext_vector_type(8))) short bf16x8;
typedef __attribute__((ext_vector_type(4))) float f32x4;

__device__ __forceinline__ unsigned short f2bf_rne(float f) {
    unsigned int u = __float_as_uint(f);
    u += 0x7FFFu + ((u >> 16) & 1u);
    return (unsigned short)(u >> 16);
}
__device__ __forceinline__ float bf2f(unsigned short h) {
    return __uint_as_float(((unsigned int)h) << 16);
}

// 8 f32 (scaled by s) -> hi bf16x8 + residual-lo bf16x8 (fp32-accurate split)
__device__ __forceinline__ void cvt8s(const float4 a, const float4 b, float s,
                                      bf16x8* hi, bf16x8* lo) {
    float v[8] = {a.x * s, a.y * s, a.z * s, a.w * s,
                  b.x * s, b.y * s, b.z * s, b.w * s};
#pragma unroll
    for (int e = 0; e < 8; ++e) {
        unsigned short h = f2bf_rne(v[e]);
        (*hi)[e] = (short)h;
        (*lo)[e] = (short)f2bf_rne(v[e] - bf2f(h));
    }
}

// ---------- Pass 1: repack x into LANE-LINEAR MFMA fragment tiles ----------
// tile(bblk,t) = 8KB: hi[2048 shorts] then lo[2048 shorts].
// Fragment element for wave-lane i, k-chunk kf at short index kf*512 + i*8
// => each wave ds_read_b128 covers 1KB contiguous -> conflict-free.
__global__ __launch_bounds__(256, 4) void conv_x2(
    const float* __restrict__ x, unsigned short* __restrict__ xt)
{
    const int bid  = blockIdx.x;          // bblk*512 + t
    const int bblk = bid >> 9;
    const int t    = bid & 511;
    const int g    = threadIdx.x;         // 0..255
    const int kf   = g >> 6;
    const int i    = g & 63;
    const int l15  = i & 15;
    const int lg   = i >> 4;

    const float* src = x + ((size_t)(bblk * 16 + l15) * TSTEPS + t) * IN_DIM
                         + kf * 32 + lg * 8;
    const float4* p = reinterpret_cast<const float4*>(src);
    bf16x8 h, l;
    cvt8s(p[0], p[1], 2.0f, &h, &l);

    unsigned short* tile = xt + ((size_t)bblk * TSTEPS + t) * 4096;
    *(bf16x8*)(tile + g * 8)        = h;   // g*8 == kf*512 + i*8
    *(bf16x8*)(tile + 2048 + g * 8) = l;
}

// ---------- Pass 2: fused SNN, 4-wave blocks + inline-asm LDS pipeline ----
// R7 geometry (wave = 16b x 16h, all 4 SIMDs busy, MFMA 233 cyc/t/SIMD) +
// R12's verified asm pipeline (ds_read t+1 during MFMA(t), counted waits).
// Per iter t: [vmcnt(10) -> barrier] (tile t+1 landed; 2 loads/tile/wave) ->
// stage tile t+7 (2 gload_lds) -> 8 asm ds_read slot(t+1) -> NEXT regs ->
// lgkmcnt(8)+sched_barrier(0) (CURRENT frags landed; this iter's 8 in
// flight) -> 12 MFMA + recurrence. asm volatile order is binding.
__global__ __launch_bounds__(256, 1) void snn_mfma_a(
    const unsigned short* __restrict__ xt,
    const float* __restrict__ W1, const float* __restrict__ b1,
    float* __restrict__ cnt_ws)
{
    __shared__ char ring[8][8192];   // 64 KB

    const int bid  = blockIdx.x;
    const int hblk = bid >> 5;     // 0..7 ; bid%8==bblk%8 -> x-sharers co-XCD
    const int bblk = bid & 31;
    const int b0   = bblk * 16;
    const int tid  = threadIdx.x;  // 0..255
    const int wave = tid >> 6;     // 0..3
    const int lane = tid & 63;
    const int l15  = lane & 15;
    const int lg   = lane >> 4;
    const int hbase = hblk * 64 + wave * 16;

    // ---- W fragments (fp32->hi/lo once, pinned in VGPRs) ----
    bf16x8 whi[4], wlo[4];
    {
        const float* wp = W1 + (size_t)(hbase + l15) * IN_DIM + lg * 8;
#pragma unroll
        for (int kf = 0; kf < 4; ++kf) {
            const float4* p = reinterpret_cast<const float4*>(wp + kf * 32);
            cvt8s(p[0], p[1], 1.0f, &whi[kf], &wlo[kf]);
        }
    }
    const float b1h = b1[hbase + l15];

    const char* gb = (const char*)xt + (size_t)bblk * TSTEPS * 8192;
    char* lsb = &ring[0][0];
    const int woff   = wave * 2048;       // this wave stages 2KB of each tile
    const int lane16 = lane * 16;
    // 32-bit LDS byte address for asm ds_read (per-lane)
    const unsigned lbase =
        (unsigned)(unsigned long long)(__attribute__((address_space(3))) char*)&ring[0][0]
        + (unsigned)lane16;

    f32x4 mem = {0.f, 0.f, 0.f, 0.f}, cnt = {0.f, 0.f, 0.f, 0.f};

#define STAGE(TT, SLOT)                                                        \
    {                                                                          \
        const char* g_ = gb + (size_t)(TT) * 8192 + woff + lane16;             \
        char* l_ = lsb + (SLOT) * 8192 + woff;                                 \
        __builtin_amdgcn_global_load_lds((const __attribute__((address_space(1))) void*)g_,          (__attribute__((address_space(3))) void*)l_,          16, 0, 0); \
        __builtin_amdgcn_global_load_lds((const __attribute__((address_space(1))) void*)(g_ + 1024), (__attribute__((address_space(3))) void*)(l_ + 1024), 16, 0, 0); \
    }

#define RD1(OFF, DST)                                                          \
    asm volatile("ds_read_b128 %0, %1 offset:%c2"                              \
                 : "=&v"(DST) : "v"(lbase), "i"(OFF))

#define RD8A(S, FH, FL)                                                        \
    RD1((S) * 8192 + 0,    FH[0]);                                             \
    RD1((S) * 8192 + 1024, FH[1]);                                             \
    RD1((S) * 8192 + 2048, FH[2]);                                             \
    RD1((S) * 8192 + 3072, FH[3]);                                             \
    RD1((S) * 8192 + 4096, FL[0]);                                             \
    RD1((S) * 8192 + 5120, FL[1]);                                             \
    RD1((S) * 8192 + 6144, FL[2]);                                             \
    RD1((S) * 8192 + 7168, FL[3]);

#define MFMA_REC(FH, FL)                                                       \
    {                                                                          \
        f32x4 chh = {b1h, b1h, b1h, b1h};                                      \
        f32x4 chl = {0.f, 0.f, 0.f, 0.f}, clh = {0.f, 0.f, 0.f, 0.f};          \
        _Pragma("unroll")                                                      \
        for (int kf = 0; kf < 4; ++kf) {                                       \
            chh = __builtin_amdgcn_mfma_f32_16x16x32_bf16(FH[kf], whi[kf], chh, 0, 0, 0); \
            chl = __builtin_amdgcn_mfma_f32_16x16x32_bf16(FH[kf], wlo[kf], chl, 0, 0, 0); \
            clh = __builtin_amdgcn_mfma_f32_16x16x32_bf16(FL[kf], whi[kf], clh, 0, 0, 0); \
        }                                                                      \
        _Pragma("unroll")                                                      \
        for (int r = 0; r < 4; ++r) {                                          \
            float cur = (chh[r] + chl[r]) + clh[r];                            \
            float dec = fmaf(BETA, mem[r], cur);                               \
            mem[r] = (mem[r] > THRESH) ? (dec - THRESH) : dec;                 \
            cnt[r] += (mem[r] > THRESH) ? 1.0f : 0.0f;                         \
        }                                                                      \
    }

// J = compile-time 0..7 (slots literal); tb = runtime t-base of this window.
#define ITER(J, CH, CL, NH, NL)                                                \
    {                                                                          \
        asm volatile("s_waitcnt vmcnt(10)" ::: "memory");                      \
        __builtin_amdgcn_s_barrier();                                          \
        asm volatile("" ::: "memory");                                         \
        { int tt = tb + (J) + 7; if (tt > TSTEPS - 1) tt = TSTEPS - 1;         \
          STAGE(tt, ((J) + 7) & 7) }                                           \
        RD8A(((J) + 1) & 7, NH, NL)                                            \
        asm volatile("s_waitcnt lgkmcnt(8)" ::: "memory");                     \
        __builtin_amdgcn_sched_barrier(0);                                     \
        MFMA_REC(CH, CL)                                                       \
    }

    // double-buffered A fragments (asm outputs -> live ranges pinned)
    bf16x8 fAh[4], fAl[4], fBh[4], fBl[4];

    // prologue: drain W/b1 loads; stage tiles 0..6 (14 loads); tile0 -> fA
    asm volatile("s_waitcnt vmcnt(0)" ::: "memory");
#pragma unroll
    for (int j = 0; j < 7; ++j)
        STAGE(j, j)
    asm volatile("s_waitcnt vmcnt(12)" ::: "memory");   // my tile-0 loads done
    __builtin_amdgcn_s_barrier();                        // everyone's done
    asm volatile("" ::: "memory");
    RD8A(0, fAh, fAl)   // 8 outstanding; drained by ITER(0)'s lgkmcnt(8)

    for (int w = 0; w < TSTEPS / 8; ++w) {
        const int tb = w * 8;
        ITER(0, fAh, fAl, fBh, fBl)
        ITER(1, fBh, fBl, fAh, fAl)
        ITER(2, fAh, fAl, fBh, fBl)
        ITER(3, fBh, fBl, fAh, fAl)
        ITER(4, fAh, fAl, fBh, fBl)
        ITER(5, fBh, fBl, fAh, fAl)
        ITER(6, fAh, fAl, fBh, fBl)
        ITER(7, fBh, fBl, fAh, fAl)
    }
#undef ITER
#undef MFMA_REC
#undef RD8A
#undef RD1
#undef STAGE

    // store spike counts; C-layout row = lg*4+r, col = l15
    float* cp = cnt_ws + (size_t)b0 * HIDDEN + hbase + l15;
#pragma unroll
    for (int r = 0; r < 4; ++r)
        cp[(size_t)(lg * 4 + r) * HIDDEN] = cnt[r];
}

// ---------- Fallback (proven R2 path) if ws too small ----------
__global__ __launch_bounds__(256, 1) void snn_mfma_lds(
    const float* __restrict__ x, const float* __restrict__ W1,
    const float* __restrict__ b1, float* __restrict__ cnt_ws)
{
    __shared__ short ldsA[2][2][16 * IN_DIM];
    const int bid  = blockIdx.x;
    const int hblk = bid >> 5;
    const int bblk = bid & 31;
    const int b0   = bblk * 16;
    const int tid  = threadIdx.x;
    const int wave = tid >> 6;
    const int lane = tid & 63;
    const int l15  = lane & 15;
    const int lg   = lane >> 4;
    const int hbase = hblk * 64 + wave * 16;

    bf16x8 whi[4], wlo[4];
    {
        const float* wp = W1 + (size_t)(hbase + l15) * IN_DIM + lg * 8;
#pragma unroll
        for (int kf = 0; kf < 4; ++kf) {
            const float4* p = reinterpret_cast<const float4*>(wp + kf * 32);
            cvt8s(p[0], p[1], 1.0f, &whi[kf], &wlo[kf]);
        }
    }
    const float b1h = b1[hbase + l15];
    const int m_w  = wave * 4 + lg;
    const int widx = m_w * IN_DIM + ((l15 ^ (m_w & 7)) * 8);
    const float* xrow = x + ((size_t)(b0 + m_w) * TSTEPS) * IN_DIM + l15 * 8;
    int ridx[4];
#pragma unroll
    for (int kf = 0; kf < 4; ++kf)
        ridx[kf] = l15 * IN_DIM + (((lg + 4 * kf) ^ (l15 & 7)) * 8);

    f32x4 mem = {0.f, 0.f, 0.f, 0.f};
    f32x4 cnt = {0.f, 0.f, 0.f, 0.f};
    {
        const float4* p = reinterpret_cast<const float4*>(xrow);
        bf16x8 h8, l8;
        cvt8s(p[0], p[1], 2.0f, &h8, &l8);
        *(bf16x8*)&ldsA[0][0][widx] = h8;
        *(bf16x8*)&ldsA[0][1][widx] = l8;
    }
    float4 rA0, rA1, rB0, rB1;
    {
        const float4* p1 = reinterpret_cast<const float4*>(xrow + 1 * IN_DIM);
        rA0 = p1[0]; rA1 = p1[1];
        const float4* p2 = reinterpret_cast<const float4*>(xrow + 2 * IN_DIM);
        rB0 = p2[0]; rB1 = p2[1];
    }
    __syncthreads();

#define SNN_BODY(T_CUR, RC0, RC1)                                              \
    {                                                                          \
        const int buf = (T_CUR) & 1;                                           \
        if ((T_CUR) + 1 < TSTEPS) {                                            \
            bf16x8 h8, l8;                                                     \
            cvt8s(RC0, RC1, 2.0f, &h8, &l8);                                   \
            *(bf16x8*)&ldsA[buf ^ 1][0][widx] = h8;                            \
            *(bf16x8*)&ldsA[buf ^ 1][1][widx] = l8;                            \
        }                                                                      \
        bf16x8 ahi[4], alo[4];                                                 \
        _Pragma("unroll")                                                      \
        for (int kf = 0; kf < 4; ++kf) {                                       \
            ahi[kf] = *(const bf16x8*)&ldsA[buf][0][ridx[kf]];                 \
            alo[kf] = *(const bf16x8*)&ldsA[buf][1][ridx[kf]];                 \
        }                                                                      \
        {                                                                      \
            int tld = (T_CUR) + 3;                                             \
            if (tld > TSTEPS - 1) tld = TSTEPS - 1;                            \
            const float4* p = reinterpret_cast<const float4*>(                 \
                xrow + (size_t)tld * IN_DIM);                                  \
            RC0 = p[0]; RC1 = p[1];                                            \
        }                                                                      \
        f32x4 chh = {b1h, b1h, b1h, b1h};                                      \
        f32x4 chl = {0.f, 0.f, 0.f, 0.f};                                      \
        f32x4 clh = {0.f, 0.f, 0.f, 0.f};                                      \
        _Pragma("unroll")                                                      \
        for (int kf = 0; kf < 4; ++kf) {                                       \
            chh = __builtin_amdgcn_mfma_f32_16x16x32_bf16(ahi[kf], whi[kf], chh, 0, 0, 0); \
            chl = __builtin_amdgcn_mfma_f32_16x16x32_bf16(ahi[kf], wlo[kf], chl, 0, 0, 0); \
            clh = __builtin_amdgcn_mfma_f32_16x16x32_bf16(alo[kf], whi[kf], clh, 0, 0, 0); \
        }                                                                      \
        _Pragma("unroll")                                                      \
        for (int r = 0; r < 4; ++r) {                                          \
            float cur = (chh[r] + chl[r]) + clh[r];                            \
            float dec = fmaf(BETA, mem[r], cur);                               \
            mem[r] = (mem[r] > THRESH) ? (dec - THRESH) : dec;                 \
            cnt[r] += (mem[r] > THRESH) ? 1.0f : 0.0f;                         \
        }                                                                      \
        __syncthreads();                                                       \
    }

    for (int t = 0; t < TSTEPS; t += 2) {
        SNN_BODY(t,     rA0, rA1)
        SNN_BODY(t + 1, rB0, rB1)
    }
#undef SNN_BODY

    float* cp = cnt_ws + (size_t)b0 * HIDDEN + hbase + l15;
#pragma unroll
    for (int r = 0; r < 4; ++r)
        cp[(size_t)(lg * 4 + r) * HIDDEN] = cnt[r];
}

// out[b,c] = (sum_h cnt[b,h] * W2[c,h]) / T + b2[c]
__global__ __launch_bounds__(64, 1) void snn_out(
    const float* __restrict__ cnt_ws, const float* __restrict__ W2,
    const float* __restrict__ b2, float* __restrict__ out)
{
    const int b = blockIdx.x;
    const int lane = threadIdx.x;
    float c8[8];
#pragma unroll
    for (int j = 0; j < 8; ++j)
        c8[j] = cnt_ws[(size_t)b * HIDDEN + lane + 64 * j];
#pragma unroll
    for (int c = 0; c < NCLASS; ++c) {
        float s = 0.f;
#pragma unroll
        for (int j = 0; j < 8; ++j)
            s = fmaf(c8[j], W2[c * HIDDEN + lane + 64 * j], s);
#pragma unroll
        for (int off = 32; off >= 1; off >>= 1)
            s += __shfl_xor(s, off, 64);
        if (lane == c)
            out[(size_t)b * NCLASS + c] = s * (1.0f / (float)TSTEPS) + b2[c];
    }
}

extern "C" void kernel_launch(void* const* d_in, const int* in_sizes, int n_in,
                              void* d_out, int out_size, void* d_ws, size_t ws_size,
                              hipStream_t stream) {
    const float* x  = (const float*)d_in[0];
    const float* W1 = (const float*)d_in[1];
    const float* b1 = (const float*)d_in[2];
    const float* W2 = (const float*)d_in[3];
    const float* b2 = (const float*)d_in[4];
    float* out = (float*)d_out;

    const size_t NX = (size_t)BATCH * TSTEPS * IN_DIM;      // 33.55M elems
    float* cnt_ws = (float*)d_ws;                           // [B, H], 1 MB
    unsigned short* xt = (unsigned short*)((char*)d_ws + (1u << 20));
    const size_t need = (1u << 20) + 2 * NX * sizeof(unsigned short);

    if (ws_size >= need) {
        conv_x2<<<dim3(32 * TSTEPS), dim3(256), 0, stream>>>(x, xt);
        snn_mfma_a<<<dim3(256), dim3(256), 0, stream>>>(xt, W1, b1, cnt_ws);
    } else {
        snn_mfma_lds<<<dim3(256), dim3(256), 0, stream>>>(x, W1, b1, cnt_ws);
    }
    snn_out<<<dim3(BATCH), dim3(64), 0, stream>>>(cnt_ws, W2, b2, out);
}

// Round 15
// 124.547 us; speedup vs baseline: 1.9745x; 1.3945x over previous
//
#include <hip/hip_runtime.h>

#define IN_DIM  128
#define HIDDEN  512
#define NCLASS  10
#define TSTEPS  512
#define BATCH   512
#define BETA    0.9f
#define THRESH  0.15f

typedef __attribute__((ext_vector_type(8))) short bf16x8;
typedef __attribute__((ext_vector_type(4))) float f32x4;

__device__ __forceinline__ unsigned short f2bf_rne(float f) {
    unsigned int u = __float_as_uint(f);
    u += 0x7FFFu + ((u >> 16) & 1u);
    return (unsigned short)(u >> 16);
}
__device__ __forceinline__ float bf2f(unsigned short h) {
    return __uint_as_float(((unsigned int)h) << 16);
}

// 8 f32 (scaled by s) -> single bf16x8 (RNE)
__device__ __forceinline__ bf16x8 cvt8(const float4 a, const float4 b, float s) {
    float v[8] = {a.x * s, a.y * s, a.z * s, a.w * s,
                  b.x * s, b.y * s, b.z * s, b.w * s};
    bf16x8 o;
#pragma unroll
    for (int e = 0; e < 8; ++e) o[e] = (short)f2bf_rne(v[e]);
    return o;
}

// 8 f32 -> hi bf16x8 + residual-lo bf16x8 (for W1, register-resident)
__device__ __forceinline__ void cvt8s(const float4 a, const float4 b,
                                      bf16x8* hi, bf16x8* lo) {
    float v[8] = {a.x, a.y, a.z, a.w, b.x, b.y, b.z, b.w};
#pragma unroll
    for (int e = 0; e < 8; ++e) {
        unsigned short h = f2bf_rne(v[e]);
        (*hi)[e] = (short)h;
        (*lo)[e] = (short)f2bf_rne(v[e] - bf2f(h));
    }
}

// ---------- Pass 1: repack x into LANE-LINEAR bf16 fragment tiles ----------
// tile(bblk,t) = 4KB: 2048 shorts. Element for wave-lane i, k-chunk kf at
// short index kf*512 + i*8 => each wave ds_read_b128 is 1KB contiguous.
__global__ __launch_bounds__(256, 4) void conv_x3(
    const float* __restrict__ x, unsigned short* __restrict__ xt)
{
    const int bid  = blockIdx.x;          // bblk*512 + t
    const int bblk = bid >> 9;
    const int t    = bid & 511;
    const int g    = threadIdx.x;         // 0..255
    const int kf   = g >> 6;
    const int i    = g & 63;
    const int l15  = i & 15;
    const int lg   = i >> 4;

    const float* src = x + ((size_t)(bblk * 16 + l15) * TSTEPS + t) * IN_DIM
                         + kf * 32 + lg * 8;
    const float4* p = reinterpret_cast<const float4*>(src);
    unsigned short* tile = xt + ((size_t)bblk * TSTEPS + t) * 2048;
    *(bf16x8*)(tile + g * 8) = cvt8(p[0], p[1], 2.0f);
}

// ---------- Pass 2: fused SNN, bf16-x + reg-hi/lo-W, asm LDS pipeline ----
// R13's verified asm ring, tiles now 4KB (bf16 x only). W1 carries the
// precision split in registers (whi + wlo; 4 extra MFMAs, zero LDS cost).
// Per iter t: [vmcnt(5) -> barrier] (tile t+1 landed; 1 load/tile/wave) ->
// stage tile t+7 (1 gload_lds) -> 4 asm ds_read slot(t+1) -> NEXT regs ->
// lgkmcnt(4)+sched_barrier(0) (CURRENT frags landed; this iter's 4 in
// flight) -> 8 MFMA + recurrence.
__global__ __launch_bounds__(256, 1) void snn_mfma_a(
    const unsigned short* __restrict__ xt,
    const float* __restrict__ W1, const float* __restrict__ b1,
    float* __restrict__ cnt_ws)
{
    __shared__ char ring[8][4096];   // 32 KB

    const int bid  = blockIdx.x;
    const int hblk = bid >> 5;     // 0..7 ; bid%8==bblk%8 -> x-sharers co-XCD
    const int bblk = bid & 31;
    const int b0   = bblk * 16;
    const int tid  = threadIdx.x;  // 0..255
    const int wave = tid >> 6;     // 0..3
    const int lane = tid & 63;
    const int l15  = lane & 15;
    const int lg   = lane >> 4;
    const int hbase = hblk * 64 + wave * 16;

    // ---- W fragments hi+lo (register-resident precision split) ----
    bf16x8 whi[4], wlo[4];
    {
        const float* wp = W1 + (size_t)(hbase + l15) * IN_DIM + lg * 8;
#pragma unroll
        for (int kf = 0; kf < 4; ++kf) {
            const float4* p = reinterpret_cast<const float4*>(wp + kf * 32);
            cvt8s(p[0], p[1], &whi[kf], &wlo[kf]);
        }
    }
    const float b1h = b1[hbase + l15];

    const char* gb = (const char*)xt + (size_t)bblk * TSTEPS * 4096;
    char* lsb = &ring[0][0];
    const int woff   = wave * 1024;       // this wave stages 1KB of each tile
    const int lane16 = lane * 16;
    const unsigned lbase =
        (unsigned)(unsigned long long)(__attribute__((address_space(3))) char*)&ring[0][0]
        + (unsigned)lane16;

    f32x4 mem = {0.f, 0.f, 0.f, 0.f}, cnt = {0.f, 0.f, 0.f, 0.f};

#define STAGE(TT, SLOT)                                                        \
    {                                                                          \
        const char* g_ = gb + (size_t)(TT) * 4096 + woff + lane16;             \
        char* l_ = lsb + (SLOT) * 4096 + woff;                                 \
        __builtin_amdgcn_global_load_lds((const __attribute__((address_space(1))) void*)g_, (__attribute__((address_space(3))) void*)l_, 16, 0, 0); \
    }

#define RD1(OFF, DST)                                                          \
    asm volatile("ds_read_b128 %0, %1 offset:%c2"                              \
                 : "=&v"(DST) : "v"(lbase), "i"(OFF))

#define RD4A(S, F)                                                             \
    RD1((S) * 4096 + 0,    F[0]);                                              \
    RD1((S) * 4096 + 1024, F[1]);                                              \
    RD1((S) * 4096 + 2048, F[2]);                                              \
    RD1((S) * 4096 + 3072, F[3]);

#define MFMA_REC(F)                                                            \
    {                                                                          \
        f32x4 chh = {b1h, b1h, b1h, b1h};                                      \
        f32x4 chl = {0.f, 0.f, 0.f, 0.f};                                      \
        _Pragma("unroll")                                                      \
        for (int kf = 0; kf < 4; ++kf) {                                       \
            chh = __builtin_amdgcn_mfma_f32_16x16x32_bf16(F[kf], whi[kf], chh, 0, 0, 0); \
            chl = __builtin_amdgcn_mfma_f32_16x16x32_bf16(F[kf], wlo[kf], chl, 0, 0, 0); \
        }                                                                      \
        _Pragma("unroll")                                                      \
        for (int r = 0; r < 4; ++r) {                                          \
            float cur = chh[r] + chl[r];                                       \
            float dec = fmaf(BETA, mem[r], cur);                               \
            mem[r] = (mem[r] > THRESH) ? (dec - THRESH) : dec;                 \
            cnt[r] += (mem[r] > THRESH) ? 1.0f : 0.0f;                         \
        }                                                                      \
    }

// J = compile-time 0..7 (slots literal); tb = runtime t-base of this window.
#define ITER(J, CF, NF)                                                        \
    {                                                                          \
        asm volatile("s_waitcnt vmcnt(5)" ::: "memory");                       \
        __builtin_amdgcn_s_barrier();                                          \
        asm volatile("" ::: "memory");                                         \
        { int tt = tb + (J) + 7; if (tt > TSTEPS - 1) tt = TSTEPS - 1;         \
          STAGE(tt, ((J) + 7) & 7) }                                           \
        RD4A(((J) + 1) & 7, NF)                                                \
        asm volatile("s_waitcnt lgkmcnt(4)" ::: "memory");                     \
        __builtin_amdgcn_sched_barrier(0);                                     \
        MFMA_REC(CF)                                                           \
    }

    // double-buffered A fragments (asm outputs -> live ranges pinned)
    bf16x8 fA[4], fB[4];

    // prologue: drain W/b1 loads; stage tiles 0..6 (7 loads); tile0 -> fA
    asm volatile("s_waitcnt vmcnt(0)" ::: "memory");
#pragma unroll
    for (int j = 0; j < 7; ++j)
        STAGE(j, j)
    asm volatile("s_waitcnt vmcnt(6)" ::: "memory");    // my tile-0 load done
    __builtin_amdgcn_s_barrier();                        // everyone's done
    asm volatile("" ::: "memory");
    RD4A(0, fA)   // 4 outstanding; drained by ITER(0)'s lgkmcnt(4)

    for (int w = 0; w < TSTEPS / 8; ++w) {
        const int tb = w * 8;
        ITER(0, fA, fB)
        ITER(1, fB, fA)
        ITER(2, fA, fB)
        ITER(3, fB, fA)
        ITER(4, fA, fB)
        ITER(5, fB, fA)
        ITER(6, fA, fB)
        ITER(7, fB, fA)
    }
#undef ITER
#undef MFMA_REC
#undef RD4A
#undef RD1
#undef STAGE

    // store spike counts; C-layout row = lg*4+r, col = l15
    float* cp = cnt_ws + (size_t)b0 * HIDDEN + hbase + l15;
#pragma unroll
    for (int r = 0; r < 4; ++r)
        cp[(size_t)(lg * 4 + r) * HIDDEN] = cnt[r];
}

// ---------- Fallback (proven R2 path) if ws too small ----------
__global__ __launch_bounds__(256, 1) void snn_mfma_lds(
    const float* __restrict__ x, const float* __restrict__ W1,
    const float* __restrict__ b1, float* __restrict__ cnt_ws)
{
    __shared__ short ldsA[2][2][16 * IN_DIM];
    const int bid  = blockIdx.x;
    const int hblk = bid >> 5;
    const int bblk = bid & 31;
    const int b0   = bblk * 16;
    const int tid  = threadIdx.x;
    const int wave = tid >> 6;
    const int lane = tid & 63;
    const int l15  = lane & 15;
    const int lg   = lane >> 4;
    const int hbase = hblk * 64 + wave * 16;

    bf16x8 whi[4], wlo[4];
    {
        const float* wp = W1 + (size_t)(hbase + l15) * IN_DIM + lg * 8;
#pragma unroll
        for (int kf = 0; kf < 4; ++kf) {
            const float4* p = reinterpret_cast<const float4*>(wp + kf * 32);
            cvt8s(p[0], p[1], &whi[kf], &wlo[kf]);
        }
    }
    const float b1h = b1[hbase + l15];
    const int m_w  = wave * 4 + lg;
    const int widx = m_w * IN_DIM + ((l15 ^ (m_w & 7)) * 8);
    const float* xrow = x + ((size_t)(b0 + m_w) * TSTEPS) * IN_DIM + l15 * 8;
    int ridx[4];
#pragma unroll
    for (int kf = 0; kf < 4; ++kf)
        ridx[kf] = l15 * IN_DIM + (((lg + 4 * kf) ^ (l15 & 7)) * 8);

    f32x4 mem = {0.f, 0.f, 0.f, 0.f};
    f32x4 cnt = {0.f, 0.f, 0.f, 0.f};
    {
        const float4* p = reinterpret_cast<const float4*>(xrow);
        *(bf16x8*)&ldsA[0][0][widx] = cvt8(p[0], p[1], 2.0f);
    }
    float4 rA0, rA1, rB0, rB1;
    {
        const float4* p1 = reinterpret_cast<const float4*>(xrow + 1 * IN_DIM);
        rA0 = p1[0]; rA1 = p1[1];
        const float4* p2 = reinterpret_cast<const float4*>(xrow + 2 * IN_DIM);
        rB0 = p2[0]; rB1 = p2[1];
    }
    __syncthreads();

#define SNN_BODY(T_CUR, RC0, RC1)                                              \
    {                                                                          \
        const int buf = (T_CUR) & 1;                                           \
        if ((T_CUR) + 1 < TSTEPS) {                                            \
            *(bf16x8*)&ldsA[buf ^ 1][0][widx] = cvt8(RC0, RC1, 2.0f);          \
        }                                                                      \
        bf16x8 ahi[4];                                                         \
        _Pragma("unroll")                                                      \
        for (int kf = 0; kf < 4; ++kf)                                         \
            ahi[kf] = *(const bf16x8*)&ldsA[buf][0][ridx[kf]];                 \
        {                                                                      \
            int tld = (T_CUR) + 3;                                             \
            if (tld > TSTEPS - 1) tld = TSTEPS - 1;                            \
            const float4* p = reinterpret_cast<const float4*>(                 \
                xrow + (size_t)tld * IN_DIM);                                  \
            RC0 = p[0]; RC1 = p[1];                                            \
        }                                                                      \
        f32x4 chh = {b1h, b1h, b1h, b1h};                                      \
        f32x4 chl = {0.f, 0.f, 0.f, 0.f};                                      \
        _Pragma("unroll")                                                      \
        for (int kf = 0; kf < 4; ++kf) {                                       \
            chh = __builtin_amdgcn_mfma_f32_16x16x32_bf16(ahi[kf], whi[kf], chh, 0, 0, 0); \
            chl = __builtin_amdgcn_mfma_f32_16x16x32_bf16(ahi[kf], wlo[kf], chl, 0, 0, 0); \
        }                                                                      \
        _Pragma("unroll")                                                      \
        for (int r = 0; r < 4; ++r) {                                          \
            float cur = chh[r] + chl[r];                                       \
            float dec = fmaf(BETA, mem[r], cur);                               \
            mem[r] = (mem[r] > THRESH) ? (dec - THRESH) : dec;                 \
            cnt[r] += (mem[r] > THRESH) ? 1.0f : 0.0f;                         \
        }                                                                      \
        __syncthreads();                                                       \
    }

    for (int t = 0; t < TSTEPS; t += 2) {
        SNN_BODY(t,     rA0, rA1)
        SNN_BODY(t + 1, rB0, rB1)
    }
#undef SNN_BODY

    float* cp = cnt_ws + (size_t)b0 * HIDDEN + hbase + l15;
#pragma unroll
    for (int r = 0; r < 4; ++r)
        cp[(size_t)(lg * 4 + r) * HIDDEN] = cnt[r];
}

// out[b,c] = (sum_h cnt[b,h] * W2[c,h]) / T + b2[c]
__global__ __launch_bounds__(64, 1) void snn_out(
    const float* __restrict__ cnt_ws, const float* __restrict__ W2,
    const float* __restrict__ b2, float* __restrict__ out)
{
    const int b = blockIdx.x;
    const int lane = threadIdx.x;
    float c8[8];
#pragma unroll
    for (int j = 0; j < 8; ++j)
        c8[j] = cnt_ws[(size_t)b * HIDDEN + lane + 64 * j];
#pragma unroll
    for (int c = 0; c < NCLASS; ++c) {
        float s = 0.f;
#pragma unroll
        for (int j = 0; j < 8; ++j)
            s = fmaf(c8[j], W2[c * HIDDEN + lane + 64 * j], s);
#pragma unroll
        for (int off = 32; off >= 1; off >>= 1)
            s += __shfl_xor(s, off, 64);
        if (lane == c)
            out[(size_t)b * NCLASS + c] = s * (1.0f / (float)TSTEPS) + b2[c];
    }
}

extern "C" void kernel_launch(void* const* d_in, const int* in_sizes, int n_in,
                              void* d_out, int out_size, void* d_ws, size_t ws_size,
                              hipStream_t stream) {
    const float* x  = (const float*)d_in[0];
    const float* W1 = (const float*)d_in[1];
    const float* b1 = (const float*)d_in[2];
    const float* W2 = (const float*)d_in[3];
    const float* b2 = (const float*)d_in[4];
    float* out = (float*)d_out;

    const size_t NX = (size_t)BATCH * TSTEPS * IN_DIM;      // 33.55M elems
    float* cnt_ws = (float*)d_ws;                           // [B, H], 1 MB
    unsigned short* xt = (unsigned short*)((char*)d_ws + (1u << 20));
    const size_t need = (1u << 20) + NX * sizeof(unsigned short);

    if (ws_size >= need) {
        conv_x3<<<dim3(32 * TSTEPS), dim3(256), 0, stream>>>(x, xt);
        snn_mfma_a<<<dim3(256), dim3(256), 0, stream>>>(xt, W1, b1, cnt_ws);
    } else {
        snn_mfma_lds<<<dim3(256), dim3(256), 0, stream>>>(x, W1, b1, cnt_ws);
    }
    snn_out<<<dim3(BATCH), dim3(64), 0, stream>>>(cnt_ws, W2, b2, out);
}

// Round 18
// 121.399 us; speedup vs baseline: 2.0257x; 1.0259x over previous
//
#include <hip/hip_runtime.h>

#define IN_DIM  128
#define HIDDEN  512
#define NCLASS  10
#define TSTEPS  512
#define BATCH   512
#define BETA    0.9f
#define THRESH  0.15f

typedef __attribute__((ext_vector_type(8))) short bf16x8;
typedef __attribute__((ext_vector_type(4))) float f32x4;

__device__ __forceinline__ unsigned short f2bf_rne(float f) {
    unsigned int u = __float_as_uint(f);
    u += 0x7FFFu + ((u >> 16) & 1u);
    return (unsigned short)(u >> 16);
}
__device__ __forceinline__ float bf2f(unsigned short h) {
    return __uint_as_float(((unsigned int)h) << 16);
}

// 8 f32 (scaled by s) -> single bf16x8 (RNE)
__device__ __forceinline__ bf16x8 cvt8(const float4 a, const float4 b, float s) {
    float v[8] = {a.x * s, a.y * s, a.z * s, a.w * s,
                  b.x * s, b.y * s, b.z * s, b.w * s};
    bf16x8 o;
#pragma unroll
    for (int e = 0; e < 8; ++e) o[e] = (short)f2bf_rne(v[e]);
    return o;
}

// 8 f32 -> hi bf16x8 + residual-lo bf16x8 (for W1, register-resident)
__device__ __forceinline__ void cvt8s(const float4 a, const float4 b,
                                      bf16x8* hi, bf16x8* lo) {
    float v[8] = {a.x, a.y, a.z, a.w, b.x, b.y, b.z, b.w};
#pragma unroll
    for (int e = 0; e < 8; ++e) {
        unsigned short h = f2bf_rne(v[e]);
        (*hi)[e] = (short)h;
        (*lo)[e] = (short)f2bf_rne(v[e] - bf2f(h));
    }
}

// ---------- Pass 1: repack x into LANE-LINEAR bf16 fragment tiles ----------
// tile(bblk,t) = 4KB: 2048 shorts. Element for wave-lane i, k-chunk kf at
// short index kf*512 + i*8 => each wave ds_read_b128 is 1KB contiguous.
__global__ __launch_bounds__(256, 4) void conv_x3(
    const float* __restrict__ x, unsigned short* __restrict__ xt)
{
    const int bid  = blockIdx.x;          // bblk*512 + t
    const int bblk = bid >> 9;
    const int t    = bid & 511;
    const int g    = threadIdx.x;         // 0..255
    const int kf   = g >> 6;
    const int i    = g & 63;
    const int l15  = i & 15;
    const int lg   = i >> 4;

    const float* src = x + ((size_t)(bblk * 16 + l15) * TSTEPS + t) * IN_DIM
                         + kf * 32 + lg * 8;
    const float4* p = reinterpret_cast<const float4*>(src);
    unsigned short* tile = xt + ((size_t)bblk * TSTEPS + t) * 2048;
    *(bf16x8*)(tile + g * 8) = cvt8(p[0], p[1], 2.0f);
}

// ---------- Pass 2: fused SNN, 16-slot ring, barrier every 4 t ----------
// R15's verified asm pipeline; ring widened to 16 slots (64KB) so the
// slot-reuse distance (16) makes barrier-every-4-iters race-free by pure
// program-order: stage at iter t hits the slot of tile t-9, whose reads
// drained at iter t-9's lgkmcnt < the barrier the staging wave passed.
// Gate: vmcnt(2) at each barrier -> tiles <= T+4 staged by all waves,
// covering the 4 iters' lookahead reads. xt padded 8 tiles: no clamps.
__global__ __launch_bounds__(256, 1) void snn_mfma_a(
    const unsigned short* __restrict__ xt,
    const float* __restrict__ W1, const float* __restrict__ b1,
    float* __restrict__ cnt_ws)
{
    __shared__ char ring[16][4096];   // 64 KB

    const int bid  = blockIdx.x;
    const int hblk = bid >> 5;     // 0..7 ; bid%8==bblk%8 -> x-sharers co-XCD
    const int bblk = bid & 31;
    const int b0   = bblk * 16;
    const int tid  = threadIdx.x;  // 0..255
    const int wave = tid >> 6;     // 0..3
    const int lane = tid & 63;
    const int l15  = lane & 15;
    const int lg   = lane >> 4;
    const int hbase = hblk * 64 + wave * 16;

    // ---- W fragments hi+lo (register-resident precision split) ----
    bf16x8 whi[4], wlo[4];
    {
        const float* wp = W1 + (size_t)(hbase + l15) * IN_DIM + lg * 8;
#pragma unroll
        for (int kf = 0; kf < 4; ++kf) {
            const float4* p = reinterpret_cast<const float4*>(wp + kf * 32);
            cvt8s(p[0], p[1], &whi[kf], &wlo[kf]);
        }
    }
    const float b1h = b1[hbase + l15];

    const char* gb = (const char*)xt + (size_t)bblk * TSTEPS * 4096;
    char* lsb = &ring[0][0];
    const int woff   = wave * 1024;       // this wave stages 1KB of each tile
    const int lane16 = lane * 16;
    const unsigned lbase =
        (unsigned)(unsigned long long)(__attribute__((address_space(3))) char*)&ring[0][0]
        + (unsigned)lane16;

    f32x4 mem = {0.f, 0.f, 0.f, 0.f}, cnt = {0.f, 0.f, 0.f, 0.f};

#define STAGE(TT)                                                              \
    {                                                                          \
        const char* g_ = gb + (size_t)(TT) * 4096 + woff + lane16;             \
        char* l_ = lsb + ((TT) & 15) * 4096 + woff;                            \
        __builtin_amdgcn_global_load_lds((const __attribute__((address_space(1))) void*)g_, (__attribute__((address_space(3))) void*)l_, 16, 0, 0); \
    }

#define RD1(OFF, DST)                                                          \
    asm volatile("ds_read_b128 %0, %1 offset:%c2"                              \
                 : "=&v"(DST) : "v"(lbase), "i"(OFF))

#define RD4A(S, F)                                                             \
    RD1((S) * 4096 + 0,    F[0]);                                              \
    RD1((S) * 4096 + 1024, F[1]);                                              \
    RD1((S) * 4096 + 2048, F[2]);                                              \
    RD1((S) * 4096 + 3072, F[3]);

#define MFMA_REC(F)                                                            \
    {                                                                          \
        f32x4 chh = {b1h, b1h, b1h, b1h};                                      \
        f32x4 chl = {0.f, 0.f, 0.f, 0.f};                                      \
        _Pragma("unroll")                                                      \
        for (int kf = 0; kf < 4; ++kf) {                                       \
            chh = __builtin_amdgcn_mfma_f32_16x16x32_bf16(F[kf], whi[kf], chh, 0, 0, 0); \
            chl = __builtin_amdgcn_mfma_f32_16x16x32_bf16(F[kf], wlo[kf], chl, 0, 0, 0); \
        }                                                                      \
        _Pragma("unroll")                                                      \
        for (int r = 0; r < 4; ++r) {                                          \
            float cur = chh[r] + chl[r];                                       \
            float dec = fmaf(BETA, mem[r], cur);                               \
            mem[r] = (mem[r] > THRESH) ? (dec - THRESH) : dec;                 \
            cnt[r] += (mem[r] > THRESH) ? 1.0f : 0.0f;                         \
        }                                                                      \
    }

// Barrier iter (J % 4 == 0): gate vmcnt(2) -> tiles <= T+4 staged by all.
#define ITER_B(J, CF, NF)                                                      \
    {                                                                          \
        asm volatile("s_waitcnt vmcnt(2)" ::: "memory");                       \
        __builtin_amdgcn_s_barrier();                                          \
        asm volatile("" ::: "memory");                                         \
        STAGE(tb + (J) + 7)                                                    \
        RD4A((tb + (J) + 1) & 15, NF)                                          \
        asm volatile("s_waitcnt lgkmcnt(4)" ::: "memory");                     \
        __builtin_amdgcn_sched_barrier(0);                                     \
        MFMA_REC(CF)                                                           \
    }

// Non-barrier iter: no gate (slot-distance 16 makes it order-safe).
#define ITER_N(J, CF, NF)                                                      \
    {                                                                          \
        STAGE(tb + (J) + 7)                                                    \
        RD4A((tb + (J) + 1) & 15, NF)                                          \
        asm volatile("s_waitcnt lgkmcnt(4)" ::: "memory");                     \
        __builtin_amdgcn_sched_barrier(0);                                     \
        MFMA_REC(CF)                                                           \
    }

    // double-buffered A fragments (asm outputs -> live ranges pinned)
    bf16x8 fA[4], fB[4];

    // prologue: drain W/b1 loads; stage tiles 0..6; tile0 -> fA
    asm volatile("s_waitcnt vmcnt(0)" ::: "memory");
#pragma unroll
    for (int j = 0; j < 7; ++j)
        STAGE(j)
    asm volatile("s_waitcnt vmcnt(6)" ::: "memory");    // my tile-0 load done
    __builtin_amdgcn_s_barrier();                        // everyone's done
    asm volatile("" ::: "memory");
    RD4A(0, fA)   // 4 outstanding; drained by first ITER's lgkmcnt(4)

    // 16 iters per window -> all ring slots compile-time; tb advances by 16.
    for (int w = 0; w < TSTEPS / 16; ++w) {
        const int tb = w * 16;
        ITER_B(0,  fA, fB)  ITER_N(1,  fB, fA)  ITER_N(2,  fA, fB)  ITER_N(3,  fB, fA)
        ITER_B(4,  fA, fB)  ITER_N(5,  fB, fA)  ITER_N(6,  fA, fB)  ITER_N(7,  fB, fA)
        ITER_B(8,  fA, fB)  ITER_N(9,  fB, fA)  ITER_N(10, fA, fB)  ITER_N(11, fB, fA)
        ITER_B(12, fA, fB)  ITER_N(13, fB, fA)  ITER_N(14, fA, fB)  ITER_N(15, fB, fA)
    }
#undef ITER_B
#undef ITER_N
#undef MFMA_REC
#undef RD4A
#undef RD1
#undef STAGE

    // store spike counts; C-layout row = lg*4+r, col = l15
    float* cp = cnt_ws + (size_t)b0 * HIDDEN + hbase + l15;
#pragma unroll
    for (int r = 0; r < 4; ++r)
        cp[(size_t)(lg * 4 + r) * HIDDEN] = cnt[r];
}

// ---------- Fallback (proven R2 path) if ws too small ----------
__global__ __launch_bounds__(256, 1) void snn_mfma_lds(
    const float* __restrict__ x, const float* __restrict__ W1,
    const float* __restrict__ b1, float* __restrict__ cnt_ws)
{
    __shared__ short ldsA[2][2][16 * IN_DIM];
    const int bid  = blockIdx.x;
    const int hblk = bid >> 5;
    const int bblk = bid & 31;
    const int b0   = bblk * 16;
    const int tid  = threadIdx.x;
    const int wave = tid >> 6;
    const int lane = tid & 63;
    const int l15  = lane & 15;
    const int lg   = lane >> 4;
    const int hbase = hblk * 64 + wave * 16;

    bf16x8 whi[4], wlo[4];
    {
        const float* wp = W1 + (size_t)(hbase + l15) * IN_DIM + lg * 8;
#pragma unroll
        for (int kf = 0; kf < 4; ++kf) {
            const float4* p = reinterpret_cast<const float4*>(wp + kf * 32);
            cvt8s(p[0], p[1], &whi[kf], &wlo[kf]);
        }
    }
    const float b1h = b1[hbase + l15];
    const int m_w  = wave * 4 + lg;
    const int widx = m_w * IN_DIM + ((l15 ^ (m_w & 7)) * 8);
    const float* xrow = x + ((size_t)(b0 + m_w) * TSTEPS) * IN_DIM + l15 * 8;
    int ridx[4];
#pragma unroll
    for (int kf = 0; kf < 4; ++kf)
        ridx[kf] = l15 * IN_DIM + (((lg + 4 * kf) ^ (l15 & 7)) * 8);

    f32x4 mem = {0.f, 0.f, 0.f, 0.f};
    f32x4 cnt = {0.f, 0.f, 0.f, 0.f};
    {
        const float4* p = reinterpret_cast<const float4*>(xrow);
        *(bf16x8*)&ldsA[0][0][widx] = cvt8(p[0], p[1], 2.0f);
    }
    float4 rA0, rA1, rB0, rB1;
    {
        const float4* p1 = reinterpret_cast<const float4*>(xrow + 1 * IN_DIM);
        rA0 = p1[0]; rA1 = p1[1];
        const float4* p2 = reinterpret_cast<const float4*>(xrow + 2 * IN_DIM);
        rB0 = p2[0]; rB1 = p2[1];
    }
    __syncthreads();

#define SNN_BODY(T_CUR, RC0, RC1)                                              \
    {                                                                          \
        const int buf = (T_CUR) & 1;                                           \
        if ((T_CUR) + 1 < TSTEPS) {                                            \
            *(bf16x8*)&ldsA[buf ^ 1][0][widx] = cvt8(RC0, RC1, 2.0f);          \
        }                                                                      \
        bf16x8 ahi[4];                                                         \
        _Pragma("unroll")                                                      \
        for (int kf = 0; kf < 4; ++kf)                                         \
            ahi[kf] = *(const bf16x8*)&ldsA[buf][0][ridx[kf]];                 \
        {                                                                      \
            int tld = (T_CUR) + 3;                                             \
            if (tld > TSTEPS - 1) tld = TSTEPS - 1;                            \
            const float4* p = reinterpret_cast<const float4*>(                 \
                xrow + (size_t)tld * IN_DIM);                                  \
            RC0 = p[0]; RC1 = p[1];                                            \
        }                                                                      \
        f32x4 chh = {b1h, b1h, b1h, b1h};                                      \
        f32x4 chl = {0.f, 0.f, 0.f, 0.f};                                      \
        _Pragma("unroll")                                                      \
        for (int kf = 0; kf < 4; ++kf) {                                       \
            chh = __builtin_amdgcn_mfma_f32_16x16x32_bf16(ahi[kf], whi[kf], chh, 0, 0, 0); \
            chl = __builtin_amdgcn_mfma_f32_16x16x32_bf16(ahi[kf], wlo[kf], chl, 0, 0, 0); \
        }                                                                      \
        _Pragma("unroll")                                                      \
        for (int r = 0; r < 4; ++r) {                                          \
            float cur = chh[r] + chl[r];                                       \
            float dec = fmaf(BETA, mem[r], cur);                               \
            mem[r] = (mem[r] > THRESH) ? (dec - THRESH) : dec;                 \
            cnt[r] += (mem[r] > THRESH) ? 1.0f : 0.0f;                         \
        }                                                                      \
        __syncthreads();                                                       \
    }

    for (int t = 0; t < TSTEPS; t += 2) {
        SNN_BODY(t,     rA0, rA1)
        SNN_BODY(t + 1, rB0, rB1)
    }
#undef SNN_BODY

    float* cp = cnt_ws + (size_t)b0 * HIDDEN + hbase + l15;
#pragma unroll
    for (int r = 0; r < 4; ++r)
        cp[(size_t)(lg * 4 + r) * HIDDEN] = cnt[r];
}

// out[b,c] = (sum_h cnt[b,h] * W2[c,h]) / T + b2[c]
__global__ __launch_bounds__(64, 1) void snn_out(
    const float* __restrict__ cnt_ws, const float* __restrict__ W2,
    const float* __restrict__ b2, float* __restrict__ out)
{
    const int b = blockIdx.x;
    const int lane = threadIdx.x;
    float c8[8];
#pragma unroll
    for (int j = 0; j < 8; ++j)
        c8[j] = cnt_ws[(size_t)b * HIDDEN + lane + 64 * j];
#pragma unroll
    for (int c = 0; c < NCLASS; ++c) {
        float s = 0.f;
#pragma unroll
        for (int j = 0; j < 8; ++j)
            s = fmaf(c8[j], W2[c * HIDDEN + lane + 64 * j], s);
#pragma unroll
        for (int off = 32; off >= 1; off >>= 1)
            s += __shfl_xor(s, off, 64);
        if (lane == c)
            out[(size_t)b * NCLASS + c] = s * (1.0f / (float)TSTEPS) + b2[c];
    }
}

extern "C" void kernel_launch(void* const* d_in, const int* in_sizes, int n_in,
                              void* d_out, int out_size, void* d_ws, size_t ws_size,
                              hipStream_t stream) {
    const float* x  = (const float*)d_in[0];
    const float* W1 = (const float*)d_in[1];
    const float* b1 = (const float*)d_in[2];
    const float* W2 = (const float*)d_in[3];
    const float* b2 = (const float*)d_in[4];
    float* out = (float*)d_out;

    const size_t NX = (size_t)BATCH * TSTEPS * IN_DIM;      // 33.55M elems
    float* cnt_ws = (float*)d_ws;                           // [B, H], 1 MB
    unsigned short* xt = (unsigned short*)((char*)d_ws + (1u << 20));
    // +8 pad tiles (16K shorts): reads/stages past t=511 are valid-but-unused
    const size_t need = (1u << 20) + (NX + 8 * 2048) * sizeof(unsigned short);

    if (ws_size >= need) {
        conv_x3<<<dim3(32 * TSTEPS), dim3(256), 0, stream>>>(x, xt);
        snn_mfma_a<<<dim3(256), dim3(256), 0, stream>>>(xt, W1, b1, cnt_ws);
    } else {
        snn_mfma_lds<<<dim3(256), dim3(256), 0, stream>>>(x, W1, b1, cnt_ws);
    }
    snn_out<<<dim3(BATCH), dim3(64), 0, stream>>>(cnt_ws, W2, b2, out);
}

// Round 19
// 118.054 us; speedup vs baseline: 2.0831x; 1.0283x over previous
//
#include <hip/hip_runtime.h>

#define IN_DIM  128
#define HIDDEN  512
#define NCLASS  10
#define TSTEPS  512
#define BATCH   512
#define BETA    0.9f
#define THRESH  0.15f

typedef __attribute__((ext_vector_type(8))) short bf16x8;
typedef __attribute__((ext_vector_type(4))) float f32x4;

__device__ __forceinline__ unsigned short f2bf_rne(float f) {
    unsigned int u = __float_as_uint(f);
    u += 0x7FFFu + ((u >> 16) & 1u);
    return (unsigned short)(u >> 16);
}
__device__ __forceinline__ float bf2f(unsigned short h) {
    return __uint_as_float(((unsigned int)h) << 16);
}

// 8 f32 (scaled by s) -> single bf16x8 (RNE)
__device__ __forceinline__ bf16x8 cvt8(const float4 a, const float4 b, float s) {
    float v[8] = {a.x * s, a.y * s, a.z * s, a.w * s,
                  b.x * s, b.y * s, b.z * s, b.w * s};
    bf16x8 o;
#pragma unroll
    for (int e = 0; e < 8; ++e) o[e] = (short)f2bf_rne(v[e]);
    return o;
}

// 8 f32 -> hi bf16x8 + residual-lo bf16x8 (for W1, register-resident)
__device__ __forceinline__ void cvt8s(const float4 a, const float4 b,
                                      bf16x8* hi, bf16x8* lo) {
    float v[8] = {a.x, a.y, a.z, a.w, b.x, b.y, b.z, b.w};
#pragma unroll
    for (int e = 0; e < 8; ++e) {
        unsigned short h = f2bf_rne(v[e]);
        (*hi)[e] = (short)h;
        (*lo)[e] = (short)f2bf_rne(v[e] - bf2f(h));
    }
}

// ---------- Pass 1: repack x into LANE-LINEAR bf16 fragment tiles ----------
// tile(bblk,t) = 4KB: 2048 shorts. Element for wave-lane i, k-chunk kf at
// short index kf*512 + i*8 => each wave ds_read_b128 is 1KB contiguous.
__global__ __launch_bounds__(256, 4) void conv_x3(
    const float* __restrict__ x, unsigned short* __restrict__ xt)
{
    const int bid  = blockIdx.x;          // bblk*512 + t
    const int bblk = bid >> 9;
    const int t    = bid & 511;
    const int g    = threadIdx.x;         // 0..255
    const int kf   = g >> 6;
    const int i    = g & 63;
    const int l15  = i & 15;
    const int lg   = i >> 4;

    const float* src = x + ((size_t)(bblk * 16 + l15) * TSTEPS + t) * IN_DIM
                         + kf * 32 + lg * 8;
    const float4* p = reinterpret_cast<const float4*>(src);
    unsigned short* tile = xt + ((size_t)bblk * TSTEPS + t) * 2048;
    *(bf16x8*)(tile + g * 8) = cvt8(p[0], p[1], 2.0f);
}

// ---------- Pass 2: fused SNN, 2-stage accumulator pipeline ----------
// R18 ring (16 slots, barrier/4t) + NEW: recurrence(t-1) runs while the
// matrix pipe chews MFMA(t). Two acc sets (hA/lA even t, hB/lB odd t);
// iter t issues MFMA(t) into its set, then RECs the OTHER set (completed
// a full iteration ago -> zero exposed MFMA latency; REC VALU has no dep
// on this iter's MFMAs so it fills the dependent-MFMA stall slots).
// REC at t=0 sees zero-init B: beta*0+0=0, no spike -> provable no-op.
__global__ __launch_bounds__(256, 1) void snn_mfma_a(
    const unsigned short* __restrict__ xt,
    const float* __restrict__ W1, const float* __restrict__ b1,
    float* __restrict__ cnt_ws)
{
    __shared__ char ring[16][4096];   // 64 KB

    const int bid  = blockIdx.x;
    const int hblk = bid >> 5;     // 0..7 ; bid%8==bblk%8 -> x-sharers co-XCD
    const int bblk = bid & 31;
    const int b0   = bblk * 16;
    const int tid  = threadIdx.x;  // 0..255
    const int wave = tid >> 6;     // 0..3
    const int lane = tid & 63;
    const int l15  = lane & 15;
    const int lg   = lane >> 4;
    const int hbase = hblk * 64 + wave * 16;

    // ---- W fragments hi+lo (register-resident precision split) ----
    bf16x8 whi[4], wlo[4];
    {
        const float* wp = W1 + (size_t)(hbase + l15) * IN_DIM + lg * 8;
#pragma unroll
        for (int kf = 0; kf < 4; ++kf) {
            const float4* p = reinterpret_cast<const float4*>(wp + kf * 32);
            cvt8s(p[0], p[1], &whi[kf], &wlo[kf]);
        }
    }
    const float b1h = b1[hbase + l15];

    const char* gb = (const char*)xt + (size_t)bblk * TSTEPS * 4096;
    char* lsb = &ring[0][0];
    const int woff   = wave * 1024;       // this wave stages 1KB of each tile
    const int lane16 = lane * 16;
    const unsigned lbase =
        (unsigned)(unsigned long long)(__attribute__((address_space(3))) char*)&ring[0][0]
        + (unsigned)lane16;

    f32x4 mem = {0.f, 0.f, 0.f, 0.f}, cnt = {0.f, 0.f, 0.f, 0.f};

#define STAGE(TT)                                                              \
    {                                                                          \
        const char* g_ = gb + (size_t)(TT) * 4096 + woff + lane16;             \
        char* l_ = lsb + ((TT) & 15) * 4096 + woff;                            \
        __builtin_amdgcn_global_load_lds((const __attribute__((address_space(1))) void*)g_, (__attribute__((address_space(3))) void*)l_, 16, 0, 0); \
    }

#define RD1(OFF, DST)                                                          \
    asm volatile("ds_read_b128 %0, %1 offset:%c2"                              \
                 : "=&v"(DST) : "v"(lbase), "i"(OFF))

#define RD4A(S, F)                                                             \
    RD1((S) * 4096 + 0,    F[0]);                                              \
    RD1((S) * 4096 + 1024, F[1]);                                              \
    RD1((S) * 4096 + 2048, F[2]);                                              \
    RD1((S) * 4096 + 3072, F[3]);

// Issue MFMA(t) into acc set (CH,CL); fresh init each t.
#define MFMA_ACC(F, CH, CL)                                                    \
    CH = (f32x4){b1h, b1h, b1h, b1h};                                          \
    CL = (f32x4){0.f, 0.f, 0.f, 0.f};                                          \
    _Pragma("unroll")                                                          \
    for (int kf = 0; kf < 4; ++kf) {                                           \
        CH = __builtin_amdgcn_mfma_f32_16x16x32_bf16(F[kf], whi[kf], CH, 0, 0, 0); \
        CL = __builtin_amdgcn_mfma_f32_16x16x32_bf16(F[kf], wlo[kf], CL, 0, 0, 0); \
    }

// LIF recurrence from the PREVIOUS iteration's acc set (no dep on this
// iter's MFMAs -> compiler sinks these VALU ops into MFMA stall slots).
#define REC(PH, PL)                                                            \
    _Pragma("unroll")                                                          \
    for (int r = 0; r < 4; ++r) {                                              \
        float cur = PH[r] + PL[r];                                             \
        float dec = fmaf(BETA, mem[r], cur);                                   \
        mem[r] = (mem[r] > THRESH) ? (dec - THRESH) : dec;                     \
        cnt[r] += (mem[r] > THRESH) ? 1.0f : 0.0f;                             \
    }

// Barrier iter (J % 4 == 0): gate vmcnt(2) -> tiles <= T+4 staged by all.
#define ITER_B(J, CF, NF, CH, CL, PH, PL)                                      \
    {                                                                          \
        asm volatile("s_waitcnt vmcnt(2)" ::: "memory");                       \
        __builtin_amdgcn_s_barrier();                                          \
        asm volatile("" ::: "memory");                                         \
        STAGE(tb + (J) + 7)                                                    \
        RD4A((tb + (J) + 1) & 15, NF)                                          \
        asm volatile("s_waitcnt lgkmcnt(4)" ::: "memory");                     \
        __builtin_amdgcn_sched_barrier(0);                                     \
        MFMA_ACC(CF, CH, CL)                                                   \
        REC(PH, PL)                                                            \
    }

// Non-barrier iter: no gate (slot-distance 16 makes it order-safe).
#define ITER_N(J, CF, NF, CH, CL, PH, PL)                                      \
    {                                                                          \
        STAGE(tb + (J) + 7)                                                    \
        RD4A((tb + (J) + 1) & 15, NF)                                          \
        asm volatile("s_waitcnt lgkmcnt(4)" ::: "memory");                     \
        __builtin_amdgcn_sched_barrier(0);                                     \
        MFMA_ACC(CF, CH, CL)                                                   \
        REC(PH, PL)                                                            \
    }

    // double-buffered A fragments + double acc sets (static names)
    bf16x8 fA[4], fB[4];
    f32x4 hA, lA, hB, lB;
    hB = (f32x4){0.f, 0.f, 0.f, 0.f};   // REC at t=0 is a no-op (mem=0)
    lB = (f32x4){0.f, 0.f, 0.f, 0.f};

    // prologue: drain W/b1 loads; stage tiles 0..6; tile0 -> fA
    asm volatile("s_waitcnt vmcnt(0)" ::: "memory");
#pragma unroll
    for (int j = 0; j < 7; ++j)
        STAGE(j)
    asm volatile("s_waitcnt vmcnt(6)" ::: "memory");    // my tile-0 load done
    __builtin_amdgcn_s_barrier();                        // everyone's done
    asm volatile("" ::: "memory");
    RD4A(0, fA)   // 4 outstanding; drained by first ITER's lgkmcnt(4)

    // 16 iters/window; acc parity == frag parity == t&1.
    for (int w = 0; w < TSTEPS / 16; ++w) {
        const int tb = w * 16;
        ITER_B(0,  fA, fB, hA, lA, hB, lB)  ITER_N(1,  fB, fA, hB, lB, hA, lA)
        ITER_N(2,  fA, fB, hA, lA, hB, lB)  ITER_N(3,  fB, fA, hB, lB, hA, lA)
        ITER_B(4,  fA, fB, hA, lA, hB, lB)  ITER_N(5,  fB, fA, hB, lB, hA, lA)
        ITER_N(6,  fA, fB, hA, lA, hB, lB)  ITER_N(7,  fB, fA, hB, lB, hA, lA)
        ITER_B(8,  fA, fB, hA, lA, hB, lB)  ITER_N(9,  fB, fA, hB, lB, hA, lA)
        ITER_N(10, fA, fB, hA, lA, hB, lB)  ITER_N(11, fB, fA, hB, lB, hA, lA)
        ITER_B(12, fA, fB, hA, lA, hB, lB)  ITER_N(13, fB, fA, hB, lB, hA, lA)
        ITER_N(14, fA, fB, hA, lA, hB, lB)  ITER_N(15, fB, fA, hB, lB, hA, lA)
    }
    // epilogue: recurrence for t=511 (computed into B)
    REC(hB, lB)
#undef ITER_B
#undef ITER_N
#undef REC
#undef MFMA_ACC
#undef RD4A
#undef RD1
#undef STAGE

    // store spike counts; C-layout row = lg*4+r, col = l15
    float* cp = cnt_ws + (size_t)b0 * HIDDEN + hbase + l15;
#pragma unroll
    for (int r = 0; r < 4; ++r)
        cp[(size_t)(lg * 4 + r) * HIDDEN] = cnt[r];
}

// ---------- Fallback (proven R2 path) if ws too small ----------
__global__ __launch_bounds__(256, 1) void snn_mfma_lds(
    const float* __restrict__ x, const float* __restrict__ W1,
    const float* __restrict__ b1, float* __restrict__ cnt_ws)
{
    __shared__ short ldsA[2][2][16 * IN_DIM];
    const int bid  = blockIdx.x;
    const int hblk = bid >> 5;
    const int bblk = bid & 31;
    const int b0   = bblk * 16;
    const int tid  = threadIdx.x;
    const int wave = tid >> 6;
    const int lane = tid & 63;
    const int l15  = lane & 15;
    const int lg   = lane >> 4;
    const int hbase = hblk * 64 + wave * 16;

    bf16x8 whi[4], wlo[4];
    {
        const float* wp = W1 + (size_t)(hbase + l15) * IN_DIM + lg * 8;
#pragma unroll
        for (int kf = 0; kf < 4; ++kf) {
            const float4* p = reinterpret_cast<const float4*>(wp + kf * 32);
            cvt8s(p[0], p[1], &whi[kf], &wlo[kf]);
        }
    }
    const float b1h = b1[hbase + l15];
    const int m_w  = wave * 4 + lg;
    const int widx = m_w * IN_DIM + ((l15 ^ (m_w & 7)) * 8);
    const float* xrow = x + ((size_t)(b0 + m_w) * TSTEPS) * IN_DIM + l15 * 8;
    int ridx[4];
#pragma unroll
    for (int kf = 0; kf < 4; ++kf)
        ridx[kf] = l15 * IN_DIM + (((lg + 4 * kf) ^ (l15 & 7)) * 8);

    f32x4 mem = {0.f, 0.f, 0.f, 0.f};
    f32x4 cnt = {0.f, 0.f, 0.f, 0.f};
    {
        const float4* p = reinterpret_cast<const float4*>(xrow);
        *(bf16x8*)&ldsA[0][0][widx] = cvt8(p[0], p[1], 2.0f);
    }
    float4 rA0, rA1, rB0, rB1;
    {
        const float4* p1 = reinterpret_cast<const float4*>(xrow + 1 * IN_DIM);
        rA0 = p1[0]; rA1 = p1[1];
        const float4* p2 = reinterpret_cast<const float4*>(xrow + 2 * IN_DIM);
        rB0 = p2[0]; rB1 = p2[1];
    }
    __syncthreads();

#define SNN_BODY(T_CUR, RC0, RC1)                                              \
    {                                                                          \
        const int buf = (T_CUR) & 1;                                           \
        if ((T_CUR) + 1 < TSTEPS) {                                            \
            *(bf16x8*)&ldsA[buf ^ 1][0][widx] = cvt8(RC0, RC1, 2.0f);          \
        }                                                                      \
        bf16x8 ahi[4];                                                         \
        _Pragma("unroll")                                                      \
        for (int kf = 0; kf < 4; ++kf)                                         \
            ahi[kf] = *(const bf16x8*)&ldsA[buf][0][ridx[kf]];                 \
        {                                                                      \
            int tld = (T_CUR) + 3;                                             \
            if (tld > TSTEPS - 1) tld = TSTEPS - 1;                            \
            const float4* p = reinterpret_cast<const float4*>(                 \
                xrow + (size_t)tld * IN_DIM);                                  \
            RC0 = p[0]; RC1 = p[1];                                            \
        }                                                                      \
        f32x4 chh = {b1h, b1h, b1h, b1h};                                      \
        f32x4 chl = {0.f, 0.f, 0.f, 0.f};                                      \
        _Pragma("unroll")                                                      \
        for (int kf = 0; kf < 4; ++kf) {                                       \
            chh = __builtin_amdgcn_mfma_f32_16x16x32_bf16(ahi[kf], whi[kf], chh, 0, 0, 0); \
            chl = __builtin_amdgcn_mfma_f32_16x16x32_bf16(ahi[kf], wlo[kf], chl, 0, 0, 0); \
        }                                                                      \
        _Pragma("unroll")                                                      \
        for (int r = 0; r < 4; ++r) {                                          \
            float cur = chh[r] + chl[r];                                       \
            float dec = fmaf(BETA, mem[r], cur);                               \
            mem[r] = (mem[r] > THRESH) ? (dec - THRESH) : dec;                 \
            cnt[r] += (mem[r] > THRESH) ? 1.0f : 0.0f;                         \
        }                                                                      \
        __syncthreads();                                                       \
    }

    for (int t = 0; t < TSTEPS; t += 2) {
        SNN_BODY(t,     rA0, rA1)
        SNN_BODY(t + 1, rB0, rB1)
    }
#undef SNN_BODY

    float* cp = cnt_ws + (size_t)b0 * HIDDEN + hbase + l15;
#pragma unroll
    for (int r = 0; r < 4; ++r)
        cp[(size_t)(lg * 4 + r) * HIDDEN] = cnt[r];
}

// out[b,c] = (sum_h cnt[b,h] * W2[c,h]) / T + b2[c]
__global__ __launch_bounds__(64, 1) void snn_out(
    const float* __restrict__ cnt_ws, const float* __restrict__ W2,
    const float* __restrict__ b2, float* __restrict__ out)
{
    const int b = blockIdx.x;
    const int lane = threadIdx.x;
    float c8[8];
#pragma unroll
    for (int j = 0; j < 8; ++j)
        c8[j] = cnt_ws[(size_t)b * HIDDEN + lane + 64 * j];
#pragma unroll
    for (int c = 0; c < NCLASS; ++c) {
        float s = 0.f;
#pragma unroll
        for (int j = 0; j < 8; ++j)
            s = fmaf(c8[j], W2[c * HIDDEN + lane + 64 * j], s);
#pragma unroll
        for (int off = 32; off >= 1; off >>= 1)
            s += __shfl_xor(s, off, 64);
        if (lane == c)
            out[(size_t)b * NCLASS + c] = s * (1.0f / (float)TSTEPS) + b2[c];
    }
}

extern "C" void kernel_launch(void* const* d_in, const int* in_sizes, int n_in,
                              void* d_out, int out_size, void* d_ws, size_t ws_size,
                              hipStream_t stream) {
    const float* x  = (const float*)d_in[0];
    const float* W1 = (const float*)d_in[1];
    const float* b1 = (const float*)d_in[2];
    const float* W2 = (const float*)d_in[3];
    const float* b2 = (const float*)d_in[4];
    float* out = (float*)d_out;

    const size_t NX = (size_t)BATCH * TSTEPS * IN_DIM;      // 33.55M elems
    float* cnt_ws = (float*)d_ws;                           // [B, H], 1 MB
    unsigned short* xt = (unsigned short*)((char*)d_ws + (1u << 20));
    // +8 pad tiles (16K shorts): reads/stages past t=511 are valid-but-unused
    const size_t need = (1u << 20) + (NX + 8 * 2048) * sizeof(unsigned short);

    if (ws_size >= need) {
        conv_x3<<<dim3(32 * TSTEPS), dim3(256), 0, stream>>>(x, xt);
        snn_mfma_a<<<dim3(256), dim3(256), 0, stream>>>(xt, W1, b1, cnt_ws);
    } else {
        snn_mfma_lds<<<dim3(256), dim3(256), 0, stream>>>(x, W1, b1, cnt_ws);
    }
    snn_out<<<dim3(BATCH), dim3(64), 0, stream>>>(cnt_ws, W2, b2, out);
}

// Round 20
// 116.833 us; speedup vs baseline: 2.1049x; 1.0104x over previous
//
#include <hip/hip_runtime.h>

#define IN_DIM  128
#define HIDDEN  512
#define NCLASS  10
#define TSTEPS  512
#define BATCH   512
#define BETA    0.9f
#define THRESH  0.15f

typedef __attribute__((ext_vector_type(8))) short bf16x8;
typedef __attribute__((ext_vector_type(4))) float f32x4;

__device__ __forceinline__ unsigned short f2bf_rne(float f) {
    unsigned int u = __float_as_uint(f);
    u += 0x7FFFu + ((u >> 16) & 1u);
    return (unsigned short)(u >> 16);
}
__device__ __forceinline__ float bf2f(unsigned short h) {
    return __uint_as_float(((unsigned int)h) << 16);
}

// 8 f32 (scaled by s) -> single bf16x8 (RNE)
__device__ __forceinline__ bf16x8 cvt8(const float4 a, const float4 b, float s) {
    float v[8] = {a.x * s, a.y * s, a.z * s, a.w * s,
                  b.x * s, b.y * s, b.z * s, b.w * s};
    bf16x8 o;
#pragma unroll
    for (int e = 0; e < 8; ++e) o[e] = (short)f2bf_rne(v[e]);
    return o;
}

// 8 f32 -> hi bf16x8 + residual-lo bf16x8 (for W1, register-resident)
__device__ __forceinline__ void cvt8s(const float4 a, const float4 b,
                                      bf16x8* hi, bf16x8* lo) {
    float v[8] = {a.x, a.y, a.z, a.w, b.x, b.y, b.z, b.w};
#pragma unroll
    for (int e = 0; e < 8; ++e) {
        unsigned short h = f2bf_rne(v[e]);
        (*hi)[e] = (short)h;
        (*lo)[e] = (short)f2bf_rne(v[e] - bf2f(h));
    }
}

// ---------- Pass 1: repack x into LANE-LINEAR bf16 fragment tiles ----------
// tile(bblk,t) = 4KB: 2048 shorts. Element for wave-lane i, k-chunk kf at
// short index kf*512 + i*8 => each wave ds_read_b128 is 1KB contiguous.
__global__ __launch_bounds__(256, 4) void conv_x3(
    const float* __restrict__ x, unsigned short* __restrict__ xt)
{
    const int bid  = blockIdx.x;          // bblk*512 + t
    const int bblk = bid >> 9;
    const int t    = bid & 511;
    const int g    = threadIdx.x;         // 0..255
    const int kf   = g >> 6;
    const int i    = g & 63;
    const int l15  = i & 15;
    const int lg   = i >> 4;

    const float* src = x + ((size_t)(bblk * 16 + l15) * TSTEPS + t) * IN_DIM
                         + kf * 32 + lg * 8;
    const float4* p = reinterpret_cast<const float4*>(src);
    unsigned short* tile = xt + ((size_t)bblk * TSTEPS + t) * 2048;
    *(bf16x8*)(tile + g * 8) = cvt8(p[0], p[1], 2.0f);
}

// ---------- Pass 2: fused SNN, paired timesteps (4 MFMA chains) ----------
// R18 ring (16 slots, barrier/4t) + NEW: 2 timesteps per step. MFMA(t) and
// MFMA(t+1) are independent -> 16 MFMAs interleave across 4 dependency
// chains (hA,lA,hB,lB), filling the 1-wave/SIMD issue bubbles that made
// MfmaUtil+VALUBusy+LDS sum to 100% serial. Chains seed from persistent
// B1/Z0 registers as MFMA C-in (no per-t acc-init movs). Per-chain MFMA
// order unchanged -> bit-identical results.
__global__ __launch_bounds__(256, 1) void snn_mfma_a(
    const unsigned short* __restrict__ xt,
    const float* __restrict__ W1, const float* __restrict__ b1,
    float* __restrict__ cnt_ws)
{
    __shared__ char ring[16][4096];   // 64 KB

    const int bid  = blockIdx.x;
    const int hblk = bid >> 5;     // 0..7 ; bid%8==bblk%8 -> x-sharers co-XCD
    const int bblk = bid & 31;
    const int b0   = bblk * 16;
    const int tid  = threadIdx.x;  // 0..255
    const int wave = tid >> 6;     // 0..3
    const int lane = tid & 63;
    const int l15  = lane & 15;
    const int lg   = lane >> 4;
    const int hbase = hblk * 64 + wave * 16;

    // ---- W fragments hi+lo (register-resident precision split) ----
    bf16x8 whi[4], wlo[4];
    {
        const float* wp = W1 + (size_t)(hbase + l15) * IN_DIM + lg * 8;
#pragma unroll
        for (int kf = 0; kf < 4; ++kf) {
            const float4* p = reinterpret_cast<const float4*>(wp + kf * 32);
            cvt8s(p[0], p[1], &whi[kf], &wlo[kf]);
        }
    }
    const float b1h = b1[hbase + l15];
    const f32x4 B1 = {b1h, b1h, b1h, b1h};   // persistent C-in seeds
    const f32x4 Z0 = {0.f, 0.f, 0.f, 0.f};

    const char* gb = (const char*)xt + (size_t)bblk * TSTEPS * 4096;
    char* lsb = &ring[0][0];
    const int woff   = wave * 1024;       // this wave stages 1KB of each tile
    const int lane16 = lane * 16;
    const unsigned lbase =
        (unsigned)(unsigned long long)(__attribute__((address_space(3))) char*)&ring[0][0]
        + (unsigned)lane16;

    f32x4 mem = {0.f, 0.f, 0.f, 0.f}, cnt = {0.f, 0.f, 0.f, 0.f};

#define STAGE(TT)                                                              \
    {                                                                          \
        const char* g_ = gb + (size_t)(TT) * 4096 + woff + lane16;             \
        char* l_ = lsb + ((TT) & 15) * 4096 + woff;                            \
        __builtin_amdgcn_global_load_lds((const __attribute__((address_space(1))) void*)g_, (__attribute__((address_space(3))) void*)l_, 16, 0, 0); \
    }

#define RD1(OFF, DST)                                                          \
    asm volatile("ds_read_b128 %0, %1 offset:%c2"                              \
                 : "=&v"(DST) : "v"(lbase), "i"(OFF))

#define RD4A(S, F)                                                             \
    RD1((S) * 4096 + 0,    F[0]);                                              \
    RD1((S) * 4096 + 1024, F[1]);                                              \
    RD1((S) * 4096 + 2048, F[2]);                                              \
    RD1((S) * 4096 + 3072, F[3]);

// 16 MFMAs for timesteps t (F0) and t+1 (F1), 4 independent chains.
#define MFMA_PAIR(F0, F1, H0, L0, H1, L1)                                      \
    H0 = __builtin_amdgcn_mfma_f32_16x16x32_bf16(F0[0], whi[0], B1, 0, 0, 0);  \
    H1 = __builtin_amdgcn_mfma_f32_16x16x32_bf16(F1[0], whi[0], B1, 0, 0, 0);  \
    L0 = __builtin_amdgcn_mfma_f32_16x16x32_bf16(F0[0], wlo[0], Z0, 0, 0, 0);  \
    L1 = __builtin_amdgcn_mfma_f32_16x16x32_bf16(F1[0], wlo[0], Z0, 0, 0, 0);  \
    _Pragma("unroll")                                                          \
    for (int kf = 1; kf < 4; ++kf) {                                           \
        H0 = __builtin_amdgcn_mfma_f32_16x16x32_bf16(F0[kf], whi[kf], H0, 0, 0, 0); \
        H1 = __builtin_amdgcn_mfma_f32_16x16x32_bf16(F1[kf], whi[kf], H1, 0, 0, 0); \
        L0 = __builtin_amdgcn_mfma_f32_16x16x32_bf16(F0[kf], wlo[kf], L0, 0, 0, 0); \
        L1 = __builtin_amdgcn_mfma_f32_16x16x32_bf16(F1[kf], wlo[kf], L1, 0, 0, 0); \
    }

// LIF recurrence (snntorch order), sequential across t by nature.
#define REC(PH, PL)                                                            \
    _Pragma("unroll")                                                          \
    for (int r = 0; r < 4; ++r) {                                              \
        float cur = PH[r] + PL[r];                                             \
        float dec = fmaf(BETA, mem[r], cur);                                   \
        mem[r] = (mem[r] > THRESH) ? (dec - THRESH) : dec;                     \
        cnt[r] += (mem[r] > THRESH) ? 1.0f : 0.0f;                             \
    }

// Pair step: t = tb + 2J, computes frags (CF0,CF1), reads next-next pair
// into (NF0,NF1), stages tiles t+8,t+9. Barrier+gate on even J only.
#define PAIR_B(J, CF0, CF1, NF0, NF1)                                          \
    {                                                                          \
        asm volatile("s_waitcnt vmcnt(2)" ::: "memory");                       \
        __builtin_amdgcn_s_barrier();                                          \
        asm volatile("" ::: "memory");                                         \
        STAGE(tb + 2 * (J) + 8)                                                \
        STAGE(tb + 2 * (J) + 9)                                                \
        RD4A((tb + 2 * (J) + 2) & 15, NF0)                                     \
        RD4A((tb + 2 * (J) + 3) & 15, NF1)                                     \
        asm volatile("s_waitcnt lgkmcnt(8)" ::: "memory");                     \
        __builtin_amdgcn_sched_barrier(0);                                     \
        MFMA_PAIR(CF0, CF1, hA, lA, hB, lB)                                    \
        REC(hA, lA)                                                            \
        REC(hB, lB)                                                            \
    }

#define PAIR_N(J, CF0, CF1, NF0, NF1)                                          \
    {                                                                          \
        STAGE(tb + 2 * (J) + 8)                                                \
        STAGE(tb + 2 * (J) + 9)                                                \
        RD4A((tb + 2 * (J) + 2) & 15, NF0)                                     \
        RD4A((tb + 2 * (J) + 3) & 15, NF1)                                     \
        asm volatile("s_waitcnt lgkmcnt(8)" ::: "memory");                     \
        __builtin_amdgcn_sched_barrier(0);                                     \
        MFMA_PAIR(CF0, CF1, hA, lA, hB, lB)                                    \
        REC(hA, lA)                                                            \
        REC(hB, lB)                                                            \
    }

    // 4 fragment buffers (2 pairs) + 4 acc chains (asm outputs pin frags)
    bf16x8 fA[4], fB[4], fC[4], fD[4];
    f32x4 hA, lA, hB, lB;

    // prologue: drain W/b1 loads; stage tiles 0..7; frags 0,1 -> fA,fB
    asm volatile("s_waitcnt vmcnt(0)" ::: "memory");
#pragma unroll
    for (int j = 0; j < 8; ++j)
        STAGE(j)
    asm volatile("s_waitcnt vmcnt(6)" ::: "memory");    // tiles 0,1 mine done
    __builtin_amdgcn_s_barrier();                        // everyone's done
    asm volatile("" ::: "memory");
    RD4A(0, fA)
    RD4A(1, fB)   // 8 outstanding; drained by pair-0's lgkmcnt(8)

    // 8 pairs (16 t) per window; barrier every 2 pairs (4 t).
    for (int w = 0; w < TSTEPS / 16; ++w) {
        const int tb = w * 16;
        PAIR_B(0, fA, fB, fC, fD)  PAIR_N(1, fC, fD, fA, fB)
        PAIR_B(2, fA, fB, fC, fD)  PAIR_N(3, fC, fD, fA, fB)
        PAIR_B(4, fA, fB, fC, fD)  PAIR_N(5, fC, fD, fA, fB)
        PAIR_B(6, fA, fB, fC, fD)  PAIR_N(7, fC, fD, fA, fB)
    }
#undef PAIR_B
#undef PAIR_N
#undef REC
#undef MFMA_PAIR
#undef RD4A
#undef RD1
#undef STAGE

    // store spike counts; C-layout row = lg*4+r, col = l15
    float* cp = cnt_ws + (size_t)b0 * HIDDEN + hbase + l15;
#pragma unroll
    for (int r = 0; r < 4; ++r)
        cp[(size_t)(lg * 4 + r) * HIDDEN] = cnt[r];
}

// ---------- Fallback (proven R2 path) if ws too small ----------
__global__ __launch_bounds__(256, 1) void snn_mfma_lds(
    const float* __restrict__ x, const float* __restrict__ W1,
    const float* __restrict__ b1, float* __restrict__ cnt_ws)
{
    __shared__ short ldsA[2][2][16 * IN_DIM];
    const int bid  = blockIdx.x;
    const int hblk = bid >> 5;
    const int bblk = bid & 31;
    const int b0   = bblk * 16;
    const int tid  = threadIdx.x;
    const int wave = tid >> 6;
    const int lane = tid & 63;
    const int l15  = lane & 15;
    const int lg   = lane >> 4;
    const int hbase = hblk * 64 + wave * 16;

    bf16x8 whi[4], wlo[4];
    {
        const float* wp = W1 + (size_t)(hbase + l15) * IN_DIM + lg * 8;
#pragma unroll
        for (int kf = 0; kf < 4; ++kf) {
            const float4* p = reinterpret_cast<const float4*>(wp + kf * 32);
            cvt8s(p[0], p[1], &whi[kf], &wlo[kf]);
        }
    }
    const float b1h = b1[hbase + l15];
    const int m_w  = wave * 4 + lg;
    const int widx = m_w * IN_DIM + ((l15 ^ (m_w & 7)) * 8);
    const float* xrow = x + ((size_t)(b0 + m_w) * TSTEPS) * IN_DIM + l15 * 8;
    int ridx[4];
#pragma unroll
    for (int kf = 0; kf < 4; ++kf)
        ridx[kf] = l15 * IN_DIM + (((lg + 4 * kf) ^ (l15 & 7)) * 8);

    f32x4 mem = {0.f, 0.f, 0.f, 0.f};
    f32x4 cnt = {0.f, 0.f, 0.f, 0.f};
    {
        const float4* p = reinterpret_cast<const float4*>(xrow);
        *(bf16x8*)&ldsA[0][0][widx] = cvt8(p[0], p[1], 2.0f);
    }
    float4 rA0, rA1, rB0, rB1;
    {
        const float4* p1 = reinterpret_cast<const float4*>(xrow + 1 * IN_DIM);
        rA0 = p1[0]; rA1 = p1[1];
        const float4* p2 = reinterpret_cast<const float4*>(xrow + 2 * IN_DIM);
        rB0 = p2[0]; rB1 = p2[1];
    }
    __syncthreads();

#define SNN_BODY(T_CUR, RC0, RC1)                                              \
    {                                                                          \
        const int buf = (T_CUR) & 1;                                           \
        if ((T_CUR) + 1 < TSTEPS) {                                            \
            *(bf16x8*)&ldsA[buf ^ 1][0][widx] = cvt8(RC0, RC1, 2.0f);          \
        }                                                                      \
        bf16x8 ahi[4];                                                         \
        _Pragma("unroll")                                                      \
        for (int kf = 0; kf < 4; ++kf)                                         \
            ahi[kf] = *(const bf16x8*)&ldsA[buf][0][ridx[kf]];                 \
        {                                                                      \
            int tld = (T_CUR) + 3;                                             \
            if (tld > TSTEPS - 1) tld = TSTEPS - 1;                            \
            const float4* p = reinterpret_cast<const float4*>(                 \
                xrow + (size_t)tld * IN_DIM);                                  \
            RC0 = p[0]; RC1 = p[1];                                            \
        }                                                                      \
        f32x4 chh = {b1h, b1h, b1h, b1h};                                      \
        f32x4 chl = {0.f, 0.f, 0.f, 0.f};                                      \
        _Pragma("unroll")                                                      \
        for (int kf = 0; kf < 4; ++kf) {                                       \
            chh = __builtin_amdgcn_mfma_f32_16x16x32_bf16(ahi[kf], whi[kf], chh, 0, 0, 0); \
            chl = __builtin_amdgcn_mfma_f32_16x16x32_bf16(ahi[kf], wlo[kf], chl, 0, 0, 0); \
        }                                                                      \
        _Pragma("unroll")                                                      \
        for (int r = 0; r < 4; ++r) {                                          \
            float cur = chh[r] + chl[r];                                       \
            float dec = fmaf(BETA, mem[r], cur);                               \
            mem[r] = (mem[r] > THRESH) ? (dec - THRESH) : dec;                 \
            cnt[r] += (mem[r] > THRESH) ? 1.0f : 0.0f;                         \
        }                                                                      \
        __syncthreads();                                                       \
    }

    for (int t = 0; t < TSTEPS; t += 2) {
        SNN_BODY(t,     rA0, rA1)
        SNN_BODY(t + 1, rB0, rB1)
    }
#undef SNN_BODY

    float* cp = cnt_ws + (size_t)b0 * HIDDEN + hbase + l15;
#pragma unroll
    for (int r = 0; r < 4; ++r)
        cp[(size_t)(lg * 4 + r) * HIDDEN] = cnt[r];
}

// out[b,c] = (sum_h cnt[b,h] * W2[c,h]) / T + b2[c]
__global__ __launch_bounds__(64, 1) void snn_out(
    const float* __restrict__ cnt_ws, const float* __restrict__ W2,
    const float* __restrict__ b2, float* __restrict__ out)
{
    const int b = blockIdx.x;
    const int lane = threadIdx.x;
    float c8[8];
#pragma unroll
    for (int j = 0; j < 8; ++j)
        c8[j] = cnt_ws[(size_t)b * HIDDEN + lane + 64 * j];
#pragma unroll
    for (int c = 0; c < NCLASS; ++c) {
        float s = 0.f;
#pragma unroll
        for (int j = 0; j < 8; ++j)
            s = fmaf(c8[j], W2[c * HIDDEN + lane + 64 * j], s);
#pragma unroll
        for (int off = 32; off >= 1; off >>= 1)
            s += __shfl_xor(s, off, 64);
        if (lane == c)
            out[(size_t)b * NCLASS + c] = s * (1.0f / (float)TSTEPS) + b2[c];
    }
}

extern "C" void kernel_launch(void* const* d_in, const int* in_sizes, int n_in,
                              void* d_out, int out_size, void* d_ws, size_t ws_size,
                              hipStream_t stream) {
    const float* x  = (const float*)d_in[0];
    const float* W1 = (const float*)d_in[1];
    const float* b1 = (const float*)d_in[2];
    const float* W2 = (const float*)d_in[3];
    const float* b2 = (const float*)d_in[4];
    float* out = (float*)d_out;

    const size_t NX = (size_t)BATCH * TSTEPS * IN_DIM;      // 33.55M elems
    float* cnt_ws = (float*)d_ws;                           // [B, H], 1 MB
    unsigned short* xt = (unsigned short*)((char*)d_ws + (1u << 20));
    // +8 pad tiles (16K shorts): reads/stages past t=511 are valid-but-unused
    const size_t need = (1u << 20) + (NX + 8 * 2048) * sizeof(unsigned short);

    if (ws_size >= need) {
        conv_x3<<<dim3(32 * TSTEPS), dim3(256), 0, stream>>>(x, xt);
        snn_mfma_a<<<dim3(256), dim3(256), 0, stream>>>(xt, W1, b1, cnt_ws);
    } else {
        snn_mfma_lds<<<dim3(256), dim3(256), 0, stream>>>(x, W1, b1, cnt_ws);
    }
    snn_out<<<dim3(BATCH), dim3(64), 0, stream>>>(cnt_ws, W2, b2, out);
}

// Round 21
// 113.496 us; speedup vs baseline: 2.1668x; 1.0294x over previous
//
#include <hip/hip_runtime.h>

#define IN_DIM  128
#define HIDDEN  512
#define NCLASS  10
#define TSTEPS  512
#define BATCH   512
#define BETA    0.9f
#define THRESH  0.15f

typedef __attribute__((ext_vector_type(8))) short bf16x8;
typedef __attribute__((ext_vector_type(4))) float f32x4;

__device__ __forceinline__ unsigned short f2bf_rne(float f) {
    unsigned int u = __float_as_uint(f);
    u += 0x7FFFu + ((u >> 16) & 1u);
    return (unsigned short)(u >> 16);
}
__device__ __forceinline__ float bf2f(unsigned short h) {
    return __uint_as_float(((unsigned int)h) << 16);
}

// 8 f32 (scaled by s) -> single bf16x8 (RNE)
__device__ __forceinline__ bf16x8 cvt8(const float4 a, const float4 b, float s) {
    float v[8] = {a.x * s, a.y * s, a.z * s, a.w * s,
                  b.x * s, b.y * s, b.z * s, b.w * s};
    bf16x8 o;
#pragma unroll
    for (int e = 0; e < 8; ++e) o[e] = (short)f2bf_rne(v[e]);
    return o;
}

// 8 f32 -> hi bf16x8 + residual-lo bf16x8 (for W1, register-resident)
__device__ __forceinline__ void cvt8s(const float4 a, const float4 b,
                                      bf16x8* hi, bf16x8* lo) {
    float v[8] = {a.x, a.y, a.z, a.w, b.x, b.y, b.z, b.w};
#pragma unroll
    for (int e = 0; e < 8; ++e) {
        unsigned short h = f2bf_rne(v[e]);
        (*hi)[e] = (short)h;
        (*lo)[e] = (short)f2bf_rne(v[e] - bf2f(h));
    }
}

// ---------- Pass 1: repack x into LANE-LINEAR bf16 fragment tiles ----------
// tile(bblk,t) = 4KB: 2048 shorts. Element for wave-lane i, k-chunk kf at
// short index kf*512 + i*8 => per-wave 1KB contiguous loads.
__global__ __launch_bounds__(256, 4) void conv_x3(
    const float* __restrict__ x, unsigned short* __restrict__ xt)
{
    const int bid  = blockIdx.x;          // bblk*512 + t
    const int bblk = bid >> 9;
    const int t    = bid & 511;
    const int g    = threadIdx.x;         // 0..255
    const int kf   = g >> 6;
    const int i    = g & 63;
    const int l15  = i & 15;
    const int lg   = i >> 4;

    const float* src = x + ((size_t)(bblk * 16 + l15) * TSTEPS + t) * IN_DIM
                         + kf * 32 + lg * 8;
    const float4* p = reinterpret_cast<const float4*>(src);
    unsigned short* tile = xt + ((size_t)bblk * TSTEPS + t) * 2048;
    *(bf16x8*)(tile + g * 8) = cvt8(p[0], p[1], 2.0f);
}

// ---------- Pass 2: fused SNN, DIRECT global->reg pipeline, NO LDS ----------
// The lockstep-serialization fix: no LDS, no ds_read, NO BARRIERS. Each wave
// loads its 1KB-contiguous fragments straight to registers via inline-asm
// global_load_dwordx4 (SGPR base + 32-bit voffset + offset imm), 6 tiles in
// flight under counted vmcnt(24). Waves free-run -> L1 service overlaps
// other waves' MFMA instead of serializing behind a barrier.
// 8 frag slot-sets (128 VGPR) rotate mod 8; paired timesteps (4 MFMA chains)
// as R20 -> bit-identical arithmetic.
__global__ __launch_bounds__(256, 1) void snn_mfma_a(
    const unsigned short* __restrict__ xt,
    const float* __restrict__ W1, const float* __restrict__ b1,
    float* __restrict__ cnt_ws)
{
    const int bid  = blockIdx.x;
    const int hblk = bid >> 5;     // 0..7 ; bid%8==bblk%8 -> x-sharers co-XCD
    const int bblk = bid & 31;
    const int b0   = bblk * 16;
    const int tid  = threadIdx.x;  // 0..255
    const int wave = tid >> 6;     // 0..3
    const int lane = tid & 63;
    const int l15  = lane & 15;
    const int lg   = lane >> 4;
    const int hbase = hblk * 64 + wave * 16;

    // ---- W fragments hi+lo (register-resident precision split) ----
    bf16x8 whi[4], wlo[4];
    {
        const float* wp = W1 + (size_t)(hbase + l15) * IN_DIM + lg * 8;
#pragma unroll
        for (int kf = 0; kf < 4; ++kf) {
            const float4* p = reinterpret_cast<const float4*>(wp + kf * 32);
            cvt8s(p[0], p[1], &whi[kf], &wlo[kf]);
        }
    }
    const float b1h = b1[hbase + l15];
    const f32x4 B1 = {b1h, b1h, b1h, b1h};   // persistent C-in seeds
    const f32x4 Z0 = {0.f, 0.f, 0.f, 0.f};

    // wave-uniform SGPR base; per-lane 32-bit running voffset (issue order)
    const unsigned short* gbase = xt + (size_t)bblk * TSTEPS * 2048;
    unsigned voff = (unsigned)(lane * 16);

    f32x4 mem = {0.f, 0.f, 0.f, 0.f}, cnt = {0.f, 0.f, 0.f, 0.f};

// one fragment load: dst <- gbase + voff + imm   (asm: order-pinned)
#define GLD(IMM, DST)                                                          \
    asm volatile("global_load_dwordx4 %0, %1, %2 offset:%c3"                   \
                 : "=&v"(DST) : "v"(voff), "s"(gbase), "i"(IMM))

// issue one tile (4 frag loads) into slot set F; advance voff to next tile
#define STG(F)                                                                 \
    GLD(0, F[0]); GLD(1024, F[1]); GLD(2048, F[2]); GLD(3072, F[3]);           \
    voff += 4096;

// 16 MFMAs for timesteps t (F0) and t+1 (F1), 4 independent chains.
#define MFMA_PAIR(F0, F1, H0, L0, H1, L1)                                      \
    H0 = __builtin_amdgcn_mfma_f32_16x16x32_bf16(F0[0], whi[0], B1, 0, 0, 0);  \
    H1 = __builtin_amdgcn_mfma_f32_16x16x32_bf16(F1[0], whi[0], B1, 0, 0, 0);  \
    L0 = __builtin_amdgcn_mfma_f32_16x16x32_bf16(F0[0], wlo[0], Z0, 0, 0, 0);  \
    L1 = __builtin_amdgcn_mfma_f32_16x16x32_bf16(F1[0], wlo[0], Z0, 0, 0, 0);  \
    _Pragma("unroll")                                                          \
    for (int kf = 1; kf < 4; ++kf) {                                           \
        H0 = __builtin_amdgcn_mfma_f32_16x16x32_bf16(F0[kf], whi[kf], H0, 0, 0, 0); \
        H1 = __builtin_amdgcn_mfma_f32_16x16x32_bf16(F1[kf], whi[kf], H1, 0, 0, 0); \
        L0 = __builtin_amdgcn_mfma_f32_16x16x32_bf16(F0[kf], wlo[kf], L0, 0, 0, 0); \
        L1 = __builtin_amdgcn_mfma_f32_16x16x32_bf16(F1[kf], wlo[kf], L1, 0, 0, 0); \
    }

// LIF recurrence (snntorch order), sequential across t by nature.
#define REC(PH, PL)                                                            \
    _Pragma("unroll")                                                          \
    for (int r = 0; r < 4; ++r) {                                              \
        float cur = PH[r] + PL[r];                                             \
        float dec = fmaf(BETA, mem[r], cur);                                   \
        mem[r] = (mem[r] > THRESH) ? (dec - THRESH) : dec;                     \
        cnt[r] += (mem[r] > THRESH) ? 1.0f : 0.0f;                             \
    }

// Pair step: consume slot sets (C0,C1) = tiles t,t+1; issue next two tiles
// into (N0,N1). vmcnt(24) = 6 tiles (t+2..t+7) stay in flight -> tiles
// t,t+1 guaranteed landed. sched_barrier stops MFMA hoisting above the wait.
#define PAIR(C0, C1, N0, N1)                                                   \
    {                                                                          \
        STG(N0)                                                                \
        STG(N1)                                                                \
        asm volatile("s_waitcnt vmcnt(24)" ::: "memory");                      \
        __builtin_amdgcn_sched_barrier(0);                                     \
        MFMA_PAIR(C0, C1, hA, lA, hB, lB)                                      \
        REC(hA, lA)                                                            \
        REC(hB, lB)                                                            \
    }

    // 8 fragment slot-sets (tiles mod 8) + 4 acc chains
    bf16x8 s0[4], s1[4], s2[4], s3[4], s4[4], s5[4], s6[4], s7[4];
    f32x4 hA, lA, hB, lB;

    // prologue: drain W/b1 loads (their vmcnt must not mix with pipeline),
    // then issue tiles 0..5 (24 loads outstanding).
    asm volatile("s_waitcnt vmcnt(0)" ::: "memory");
    STG(s0) STG(s1) STG(s2) STG(s3) STG(s4) STG(s5)

    // 4 pairs (8 t) per window; slots rotate mod 8 -> all compile-time.
    for (int w = 0; w < TSTEPS / 8; ++w) {
        PAIR(s0, s1, s6, s7)
        PAIR(s2, s3, s0, s1)
        PAIR(s4, s5, s2, s3)
        PAIR(s6, s7, s4, s5)
    }
#undef PAIR
#undef REC
#undef MFMA_PAIR
#undef STG
#undef GLD

    // store spike counts; C-layout row = lg*4+r, col = l15
    float* cp = cnt_ws + (size_t)b0 * HIDDEN + hbase + l15;
#pragma unroll
    for (int r = 0; r < 4; ++r)
        cp[(size_t)(lg * 4 + r) * HIDDEN] = cnt[r];
}

// ---------- Fallback (proven R2 path) if ws too small ----------
__global__ __launch_bounds__(256, 1) void snn_mfma_lds(
    const float* __restrict__ x, const float* __restrict__ W1,
    const float* __restrict__ b1, float* __restrict__ cnt_ws)
{
    __shared__ short ldsA[2][2][16 * IN_DIM];
    const int bid  = blockIdx.x;
    const int hblk = bid >> 5;
    const int bblk = bid & 31;
    const int b0   = bblk * 16;
    const int tid  = threadIdx.x;
    const int wave = tid >> 6;
    const int lane = tid & 63;
    const int l15  = lane & 15;
    const int lg   = lane >> 4;
    const int hbase = hblk * 64 + wave * 16;

    bf16x8 whi[4], wlo[4];
    {
        const float* wp = W1 + (size_t)(hbase + l15) * IN_DIM + lg * 8;
#pragma unroll
        for (int kf = 0; kf < 4; ++kf) {
            const float4* p = reinterpret_cast<const float4*>(wp + kf * 32);
            cvt8s(p[0], p[1], &whi[kf], &wlo[kf]);
        }
    }
    const float b1h = b1[hbase + l15];
    const int m_w  = wave * 4 + lg;
    const int widx = m_w * IN_DIM + ((l15 ^ (m_w & 7)) * 8);
    const float* xrow = x + ((size_t)(b0 + m_w) * TSTEPS) * IN_DIM + l15 * 8;
    int ridx[4];
#pragma unroll
    for (int kf = 0; kf < 4; ++kf)
        ridx[kf] = l15 * IN_DIM + (((lg + 4 * kf) ^ (l15 & 7)) * 8);

    f32x4 mem = {0.f, 0.f, 0.f, 0.f};
    f32x4 cnt = {0.f, 0.f, 0.f, 0.f};
    {
        const float4* p = reinterpret_cast<const float4*>(xrow);
        *(bf16x8*)&ldsA[0][0][widx] = cvt8(p[0], p[1], 2.0f);
    }
    float4 rA0, rA1, rB0, rB1;
    {
        const float4* p1 = reinterpret_cast<const float4*>(xrow + 1 * IN_DIM);
        rA0 = p1[0]; rA1 = p1[1];
        const float4* p2 = reinterpret_cast<const float4*>(xrow + 2 * IN_DIM);
        rB0 = p2[0]; rB1 = p2[1];
    }
    __syncthreads();

#define SNN_BODY(T_CUR, RC0, RC1)                                              \
    {                                                                          \
        const int buf = (T_CUR) & 1;                                           \
        if ((T_CUR) + 1 < TSTEPS) {                                            \
            *(bf16x8*)&ldsA[buf ^ 1][0][widx] = cvt8(RC0, RC1, 2.0f);          \
        }                                                                      \
        bf16x8 ahi[4];                                                         \
        _Pragma("unroll")                                                      \
        for (int kf = 0; kf < 4; ++kf)                                         \
            ahi[kf] = *(const bf16x8*)&ldsA[buf][0][ridx[kf]];                 \
        {                                                                      \
            int tld = (T_CUR) + 3;                                             \
            if (tld > TSTEPS - 1) tld = TSTEPS - 1;                            \
            const float4* p = reinterpret_cast<const float4*>(                 \
                xrow + (size_t)tld * IN_DIM);                                  \
            RC0 = p[0]; RC1 = p[1];                                            \
        }                                                                      \
        f32x4 chh = {b1h, b1h, b1h, b1h};                                      \
        f32x4 chl = {0.f, 0.f, 0.f, 0.f};                                      \
        _Pragma("unroll")                                                      \
        for (int kf = 0; kf < 4; ++kf) {                                       \
            chh = __builtin_amdgcn_mfma_f32_16x16x32_bf16(ahi[kf], whi[kf], chh, 0, 0, 0); \
            chl = __builtin_amdgcn_mfma_f32_16x16x32_bf16(ahi[kf], wlo[kf], chl, 0, 0, 0); \
        }                                                                      \
        _Pragma("unroll")                                                      \
        for (int r = 0; r < 4; ++r) {                                          \
            float cur = chh[r] + chl[r];                                       \
            float dec = fmaf(BETA, mem[r], cur);                               \
            mem[r] = (mem[r] > THRESH) ? (dec - THRESH) : dec;                 \
            cnt[r] += (mem[r] > THRESH) ? 1.0f : 0.0f;                         \
        }                                                                      \
        __syncthreads();                                                       \
    }

    for (int t = 0; t < TSTEPS; t += 2) {
        SNN_BODY(t,     rA0, rA1)
        SNN_BODY(t + 1, rB0, rB1)
    }
#undef SNN_BODY

    float* cp = cnt_ws + (size_t)b0 * HIDDEN + hbase + l15;
#pragma unroll
    for (int r = 0; r < 4; ++r)
        cp[(size_t)(lg * 4 + r) * HIDDEN] = cnt[r];
}

// out[b,c] = (sum_h cnt[b,h] * W2[c,h]) / T + b2[c]
__global__ __launch_bounds__(64, 1) void snn_out(
    const float* __restrict__ cnt_ws, const float* __restrict__ W2,
    const float* __restrict__ b2, float* __restrict__ out)
{
    const int b = blockIdx.x;
    const int lane = threadIdx.x;
    float c8[8];
#pragma unroll
    for (int j = 0; j < 8; ++j)
        c8[j] = cnt_ws[(size_t)b * HIDDEN + lane + 64 * j];
#pragma unroll
    for (int c = 0; c < NCLASS; ++c) {
        float s = 0.f;
#pragma unroll
        for (int j = 0; j < 8; ++j)
            s = fmaf(c8[j], W2[c * HIDDEN + lane + 64 * j], s);
#pragma unroll
        for (int off = 32; off >= 1; off >>= 1)
            s += __shfl_xor(s, off, 64);
        if (lane == c)
            out[(size_t)b * NCLASS + c] = s * (1.0f / (float)TSTEPS) + b2[c];
    }
}

extern "C" void kernel_launch(void* const* d_in, const int* in_sizes, int n_in,
                              void* d_out, int out_size, void* d_ws, size_t ws_size,
                              hipStream_t stream) {
    const float* x  = (const float*)d_in[0];
    const float* W1 = (const float*)d_in[1];
    const float* b1 = (const float*)d_in[2];
    const float* W2 = (const float*)d_in[3];
    const float* b2 = (const float*)d_in[4];
    float* out = (float*)d_out;

    const size_t NX = (size_t)BATCH * TSTEPS * IN_DIM;      // 33.55M elems
    float* cnt_ws = (float*)d_ws;                           // [B, H], 1 MB
    unsigned short* xt = (unsigned short*)((char*)d_ws + (1u << 20));
    // +8 pad tiles (16K shorts): prefetch past t=511 is valid-but-unused
    const size_t need = (1u << 20) + (NX + 8 * 2048) * sizeof(unsigned short);

    if (ws_size >= need) {
        conv_x3<<<dim3(32 * TSTEPS), dim3(256), 0, stream>>>(x, xt);
        snn_mfma_a<<<dim3(256), dim3(256), 0, stream>>>(xt, W1, b1, cnt_ws);
    } else {
        snn_mfma_lds<<<dim3(256), dim3(256), 0, stream>>>(x, W1, b1, cnt_ws);
    }
    snn_out<<<dim3(BATCH), dim3(64), 0, stream>>>(cnt_ws, W2, b2, out);
}